// Round 1
// baseline (780.789 us; speedup 1.0000x reference)
//
#include <hip/hip_runtime.h>

typedef unsigned short ushort_t;

#define DEV __device__ __forceinline__

DEV float sigm(float x) { return 1.0f / (1.0f + __expf(-x)); }
DEV float tanh_fast(float x) { return 1.0f - 2.0f / (__expf(2.0f * x) + 1.0f); }
DEV ushort_t f2bf(float v) {
    unsigned u = __float_as_uint(v);
    unsigned r = (u + 0x7fffu + ((u >> 16) & 1u)) >> 16;
    return (ushort_t)r;
}
DEV float bf2f(ushort_t h) { return __uint_as_float(((unsigned)h) << 16); }
DEV float dot4(float4 a, float4 b) {
    return fmaf(a.x, b.x, fmaf(a.y, b.y, fmaf(a.z, b.z, a.w * b.w)));
}

// ---------------------------------------------------------------------------
// Kernel A: per-rel and per-query tables.
// grhr[r][perm 256]  : gateW[:,0:128] @ hr                  (perm: [l][k] = row l+64k)
// whr [r][64]        : Wr @ hr
// thr [r][128]       : ht_W[:,0:128] @ hr + ht_b
// gq  [q][perm 256]  : gateW[:,128:256] @ h_qr + gateW_b
// wq  [q][64]        : Wqr @ h_qr + Wqr_b
// ---------------------------------------------------------------------------
__global__ __launch_bounds__(256) void table_kernel(
    const float* __restrict__ rela, const int* __restrict__ q_rel,
    const float* __restrict__ gateW, const float* __restrict__ gateW_b,
    const float* __restrict__ WrW, const float* __restrict__ WqrW,
    const float* __restrict__ Wqr_b, const float* __restrict__ htW,
    const float* __restrict__ ht_b,
    float* __restrict__ grhr, float* __restrict__ gq,
    float* __restrict__ whr, float* __restrict__ wq,
    float* __restrict__ thr, int vocab)
{
    __shared__ float x[128];
    int b = blockIdx.x, t = threadIdx.x;
    bool isRel = b < vocab;
    int src = isRel ? b : q_rel[b - vocab];
    if (t < 128) x[t] = rela[src * 128 + t];
    __syncthreads();
    const float4* x4 = (const float4*)x;
    {
        const float4* wrow = (const float4*)(gateW + t * 384 + (isRel ? 0 : 128));
        float acc = isRel ? 0.0f : gateW_b[t];
#pragma unroll 8
        for (int i = 0; i < 32; i++) acc += dot4(wrow[i], x4[i]);
        float* dst = isRel ? (grhr + b * 256) : (gq + (b - vocab) * 256);
        dst[(t & 63) * 4 + (t >> 6)] = acc;   // row t -> perm slot
    }
    if (isRel) {
        if (t < 192) {
            bool isWr = t < 64;
            int i = isWr ? t : (t - 64);
            const float4* wrow = (const float4*)(isWr ? (WrW + i * 128) : (htW + i * 256));
            float acc = isWr ? 0.0f : ht_b[i];
#pragma unroll 8
            for (int q = 0; q < 32; q++) acc += dot4(wrow[q], x4[q]);
            if (isWr) whr[b * 64 + i] = acc;
            else      thr[b * 128 + i] = acc;
        }
    } else {
        if (t < 64) {
            const float4* wrow = (const float4*)(WqrW + t * 128);
            float acc = Wqr_b[t];
#pragma unroll 8
            for (int q = 0; q < 32; q++) acc += dot4(wrow[q], x4[q]);
            wq[(b - vocab) * 64 + t] = acc;
        }
    }
}

// ---------------------------------------------------------------------------
// Kernel B: per-node precompute (bf16 outputs).
// gate_hs[n][perm 256] : gateW[:,256:384] @ hidden[n]
// ws_hs  [n][64]       : Ws @ hidden[n]
// Block handles 16 nodes; 5 weight tiles of 64 rows staged in LDS.
// thread: nloc = t/16 (node), rr = t%16, rows rr+16m.
// ---------------------------------------------------------------------------
__global__ __launch_bounds__(256) void node_kernel(
    const float* __restrict__ hidden, const float* __restrict__ gateW,
    const float* __restrict__ WsW,
    ushort_t* __restrict__ gate_hs, ushort_t* __restrict__ ws_hs, int nNode)
{
    __shared__ float xl[16 * 132];
    __shared__ float wl[64 * 132];
    int t = threadIdx.x;
    int nloc = t >> 4, rr = t & 15;
    int nbase = blockIdx.x * 16;
    for (int idx = t; idx < 2048; idx += 256) {
        int nn = idx >> 7, j = idx & 127;
        int node = nbase + nn;
        xl[nn * 132 + j] = (node < nNode) ? hidden[node * 128 + j] : 0.0f;
    }
    const float4* xv = (const float4*)(xl + nloc * 132);
    int node = nbase + nloc;
    for (int tile = 0; tile < 5; tile++) {
        __syncthreads();
        for (int idx = t; idx < 8192; idx += 256) {
            int row = idx >> 7, j = idx & 127;
            wl[row * 132 + j] = (tile < 4) ? gateW[(tile * 64 + row) * 384 + 256 + j]
                                           : WsW[row * 128 + j];
        }
        __syncthreads();
        float a0 = 0, a1 = 0, a2 = 0, a3 = 0;
#pragma unroll 4
        for (int q = 0; q < 32; q++) {
            float4 xq = xv[q];
            float4 w0 = *(const float4*)(wl + (rr)*132 + q * 4);
            float4 w1 = *(const float4*)(wl + (rr + 16) * 132 + q * 4);
            float4 w2 = *(const float4*)(wl + (rr + 32) * 132 + q * 4);
            float4 w3 = *(const float4*)(wl + (rr + 48) * 132 + q * 4);
            a0 += dot4(w0, xq); a1 += dot4(w1, xq);
            a2 += dot4(w2, xq); a3 += dot4(w3, xq);
        }
        if (node < nNode) {
            if (tile < 4) {
                ushort_t* dst = gate_hs + (size_t)node * 256;
                dst[(rr)*4 + tile]      = f2bf(a0);
                dst[(rr + 16) * 4 + tile] = f2bf(a1);
                dst[(rr + 32) * 4 + tile] = f2bf(a2);
                dst[(rr + 48) * 4 + tile] = f2bf(a3);
            } else {
                ushort_t* dst = ws_hs + (size_t)node * 64;
                dst[rr] = f2bf(a0); dst[rr + 16] = f2bf(a1);
                dst[rr + 32] = f2bf(a2); dst[rr + 48] = f2bf(a3);
            }
        }
    }
}

// ---------------------------------------------------------------------------
// Edge kernel: 1 wave handles 8 edges per batch of 32 (4 waves/block).
// Phase 1: gates (sigmoid of 3-table sum), x = reset*hs -> LDS, attn alpha.
// Phase 2: cand matvec vs LDS-staged bf16 ht_W[:,128:256], pairs (l, l+64).
//          chunk index jj^(lane&7) spreads 512B-strided rows over all banks.
// Phase 3: message, sigmoid(alpha)*message -> atomicAdd agg; deg count.
// ---------------------------------------------------------------------------
__global__ __launch_bounds__(256) void edge_kernel(
    const int* __restrict__ edges, int nEdge, int nBatch,
    const float* __restrict__ hidden,
    const float* __restrict__ grhr, const float* __restrict__ gq,
    const float* __restrict__ whr, const float* __restrict__ wq,
    const float* __restrict__ thr,
    const ushort_t* __restrict__ gate_hs, const ushort_t* __restrict__ ws_hs,
    const float* __restrict__ walpha, const float* __restrict__ htW,
    float* __restrict__ agg, float* __restrict__ deg)
{
    __shared__ unsigned w2[64 * 128];     // (W2[l][j], W2[l+64][j]) bf16 pair
    __shared__ float xbuf[4 * 8 * 128];   // [wave][edge][j]
    int t = threadIdx.x;
    for (int idx = t; idx < 64 * 128; idx += 256) {
        int l = idx >> 7, j = idx & 127;
        unsigned lo = (unsigned)f2bf(htW[l * 256 + 128 + j]);
        unsigned hi = (unsigned)f2bf(htW[(l + 64) * 256 + 128 + j]);
        w2[idx] = lo | (hi << 16);
    }
    int w = t >> 6, l = t & 63;
    int g = l & 7;
    float wal = walpha[l];
    float* xw = xbuf + w * 1024;
    const unsigned* w2row = w2 + l * 128;

    for (int b = blockIdx.x; b < nBatch; b += gridDim.x) {
        int ebase = b * 32 + w * 8;
        float ul[8], uh[8], hl[8], hh[8], sga[8];
        int robj[8], rrel[8];
        __syncthreads();   // xbuf safe to overwrite; also covers w2 staging
#pragma unroll
        for (int e = 0; e < 8; e++) {
            int eid = ebase + e;
            bool valid = eid < nEdge;
            int ei = valid ? eid : 0;
            const int* er = edges + ei * 7;
            int ridx = er[0], rel = er[2], sub = er[4], obj = er[5];
            ushort4 gp = ((const ushort4*)gate_hs)[sub * 64 + l];
            float4 ga = ((const float4*)grhr)[rel * 64 + l];
            float4 gb = ((const float4*)gq)[ridx * 64 + l];
            float s0 = sigm(ga.x + gb.x + bf2f(gp.x));  // update[l]
            float s1 = sigm(ga.y + gb.y + bf2f(gp.y));  // update[l+64]
            float s2 = sigm(ga.z + gb.z + bf2f(gp.z));  // reset[l]
            float s3 = sigm(ga.w + gb.w + bf2f(gp.w));  // reset[l+64]
            float h0 = hidden[sub * 128 + l];
            float h1 = hidden[sub * 128 + 64 + l];
            xw[e * 128 + l] = s2 * h0;
            xw[e * 128 + 64 + l] = s3 * h1;
            float a = bf2f(ws_hs[sub * 64 + l]) + whr[rel * 64 + l] + wq[ridx * 64 + l];
            a = (a > 0.0f) ? a : 0.01f * a;
            float v = a * wal;
#pragma unroll
            for (int o = 32; o > 0; o >>= 1) v += __shfl_xor(v, o, 64);
            sga[e] = sigm(v);
            ul[e] = s0; uh[e] = s1; hl[e] = h0; hh[e] = h1;
            robj[e] = valid ? obj : -1; rrel[e] = rel;
            if (valid && l == 0) atomicAdd(deg + obj, 1.0f);
        }
        __syncthreads();   // xbuf visible to phase 2
        float cl[8], ch[8];
#pragma unroll
        for (int e = 0; e < 8; e++) {
            cl[e] = thr[rrel[e] * 128 + l];
            ch[e] = thr[rrel[e] * 128 + 64 + l];
        }
#pragma unroll 2
        for (int jj = 0; jj < 32; jj++) {
            int c = jj ^ g;
            uint4 wv = ((const uint4*)w2row)[c];
            float wl0 = __uint_as_float(wv.x << 16), wh0 = __uint_as_float(wv.x & 0xffff0000u);
            float wl1 = __uint_as_float(wv.y << 16), wh1 = __uint_as_float(wv.y & 0xffff0000u);
            float wl2 = __uint_as_float(wv.z << 16), wh2 = __uint_as_float(wv.z & 0xffff0000u);
            float wl3 = __uint_as_float(wv.w << 16), wh3 = __uint_as_float(wv.w & 0xffff0000u);
#pragma unroll
            for (int e = 0; e < 8; e++) {
                float4 x4 = ((const float4*)(xw + e * 128))[c];
                cl[e] = fmaf(wl0, x4.x, fmaf(wl1, x4.y, fmaf(wl2, x4.z, fmaf(wl3, x4.w, cl[e]))));
                ch[e] = fmaf(wh0, x4.x, fmaf(wh1, x4.y, fmaf(wh2, x4.z, fmaf(wh3, x4.w, ch[e]))));
            }
        }
#pragma unroll
        for (int e = 0; e < 8; e++) {
            float cdl = tanh_fast(cl[e]);
            float cdh = tanh_fast(ch[e]);
            float ml = (1.0f - ul[e]) * hl[e] + ul[e] * cdl;
            float mh = (1.0f - uh[e]) * hh[e] + uh[e] * cdh;
            if (robj[e] >= 0) {
                atomicAdd(agg + (size_t)robj[e] * 128 + l, sga[e] * ml);
                atomicAdd(agg + (size_t)robj[e] * 128 + 64 + l, sga[e] * mh);
            }
        }
    }
}

// ---------------------------------------------------------------------------
// Final: out[n] = (agg[n]/sqrt(deg[n]+1e-4)) @ Wh.T, in place over d_out.
// ---------------------------------------------------------------------------
__global__ __launch_bounds__(256) void final_kernel(
    const float* __restrict__ WhW, const float* __restrict__ deg,
    float* __restrict__ agg, int nNode)
{
    __shared__ unsigned whp[64 * 128];  // [jj][col] = (Wh[col][2jj], Wh[col][2jj+1]) bf16
    __shared__ float xr[2][132];
    int t = threadIdx.x;
    for (int idx = t; idx < 8192; idx += 256) {
        int col = idx >> 6, jj = idx & 63;
        unsigned lo = (unsigned)f2bf(WhW[col * 128 + 2 * jj]);
        unsigned hi = (unsigned)f2bf(WhW[col * 128 + 2 * jj + 1]);
        whp[jj * 128 + col] = lo | (hi << 16);
    }
    int nl = t >> 7, col = t & 127;
    int nPairs = (nNode + 1) >> 1;
    for (int p = blockIdx.x; p < nPairs; p += gridDim.x) {
        int n = p * 2 + nl;
        bool valid = n < nNode;
        __syncthreads();
        if (valid) {
            float d = deg[n];
            float r = 1.0f / sqrtf(d + 1e-4f);
            xr[nl][col] = agg[(size_t)n * 128 + col] * r;
        }
        __syncthreads();
        float acc = 0.0f;
#pragma unroll 8
        for (int jj = 0; jj < 64; jj++) {
            unsigned wp = whp[jj * 128 + col];
            float2 xa = *(const float2*)&xr[nl][2 * jj];
            acc = fmaf(__uint_as_float(wp << 16), xa.x, acc);
            acc = fmaf(__uint_as_float(wp & 0xffff0000u), xa.y, acc);
        }
        if (valid) agg[(size_t)n * 128 + col] = acc;
    }
}

extern "C" void kernel_launch(void* const* d_in, const int* in_sizes, int n_in,
                              void* d_out, int out_size, void* d_ws, size_t ws_size,
                              hipStream_t stream)
{
    const int*   q_rel   = (const int*)d_in[1];
    const float* hidden  = (const float*)d_in[2];
    const int*   edges   = (const int*)d_in[3];
    const float* rela    = (const float*)d_in[5];
    const float* WsW     = (const float*)d_in[6];
    const float* WrW     = (const float*)d_in[7];
    const float* WqrW    = (const float*)d_in[8];
    const float* Wqr_b   = (const float*)d_in[9];
    const float* walpha  = (const float*)d_in[10];
    const float* gateW   = (const float*)d_in[11];
    const float* gateW_b = (const float*)d_in[12];
    const float* htW     = (const float*)d_in[13];
    const float* ht_b    = (const float*)d_in[14];
    const float* WhW     = (const float*)d_in[15];

    int nNode  = in_sizes[2] / 128;
    int nEdge  = in_sizes[3] / 7;
    int vocab  = in_sizes[5] / 128;
    int nQuery = in_sizes[1];

    char* ws = (char*)d_ws;
    size_t off = 0;
    auto alloc = [&](size_t bytes) { size_t o = off; off += (bytes + 255) & ~(size_t)255; return o; };
    float*    degp    = (float*)(ws + alloc((size_t)nNode * 4));
    float*    grhr    = (float*)(ws + alloc((size_t)vocab * 256 * 4));
    float*    whr     = (float*)(ws + alloc((size_t)vocab * 64 * 4));
    float*    thr     = (float*)(ws + alloc((size_t)vocab * 128 * 4));
    float*    gq      = (float*)(ws + alloc((size_t)nQuery * 256 * 4));
    float*    wq      = (float*)(ws + alloc((size_t)nQuery * 64 * 4));
    ushort_t* gate_hs = (ushort_t*)(ws + alloc((size_t)nNode * 256 * 2));
    ushort_t* ws_hs   = (ushort_t*)(ws + alloc((size_t)nNode * 64 * 2));
    if (off > ws_size) return;  // workspace too small -> zero output (diagnostic)

    float* agg = (float*)d_out;
    hipMemsetAsync(agg, 0, (size_t)nNode * 128 * 4, stream);
    hipMemsetAsync(degp, 0, (size_t)nNode * 4, stream);

    table_kernel<<<vocab + nQuery, 256, 0, stream>>>(
        rela, q_rel, gateW, gateW_b, WrW, WqrW, Wqr_b, htW, ht_b,
        grhr, gq, whr, wq, thr, vocab);

    int ngrp = (nNode + 15) / 16;
    node_kernel<<<ngrp, 256, 0, stream>>>(hidden, gateW, WsW, gate_hs, ws_hs, nNode);

    int nBatch = (nEdge + 31) / 32;
    int egrid = nBatch < 2048 ? nBatch : 2048;
    edge_kernel<<<egrid, 256, 0, stream>>>(
        edges, nEdge, nBatch, hidden, grhr, gq, whr, wq, thr,
        gate_hs, ws_hs, walpha, htW, agg, degp);

    int pairs = (nNode + 1) / 2;
    int fgrid = pairs < 2048 ? pairs : 2048;
    final_kernel<<<fgrid, 256, 0, stream>>>(WhW, degp, agg, nNode);
}

// Round 2
// 677.893 us; speedup vs baseline: 1.1518x; 1.1518x over previous
//
#include <hip/hip_runtime.h>

typedef unsigned short ushort_t;
typedef __attribute__((ext_vector_type(8))) short short8;
typedef __attribute__((ext_vector_type(4))) float f32x4;

#define DEV __device__ __forceinline__

DEV float sigm(float x) { return 1.0f / (1.0f + __expf(-x)); }
DEV float tanh_fast(float x) { return 1.0f - 2.0f / (__expf(2.0f * x) + 1.0f); }
DEV ushort_t f2bf(float v) {
    unsigned u = __float_as_uint(v);
    unsigned r = (u + 0x7fffu + ((u >> 16) & 1u)) >> 16;
    return (ushort_t)r;
}
DEV float bf2f(ushort_t h) { return __uint_as_float(((unsigned)h) << 16); }
DEV unsigned cvt_pk(float lo, float hi) {
    unsigned r;
    asm("v_cvt_pk_bf16_f32 %0, %1, %2" : "=v"(r) : "v"(lo), "v"(hi));
    return r;
}
DEV float dot4(float4 a, float4 b) {
    return fmaf(a.x, b.x, fmaf(a.y, b.y, fmaf(a.z, b.z, a.w * b.w)));
}

// ---------------------------------------------------------------------------
// Kernel A: per-rel and per-query tables.
// grhr[r][256] : gateW[:,0:128] @ hr, packed (update_d, reset_d) pairs: slot 2d+{0,1}
// whr [r][64]  : Wr @ hr                         (natural)
// thr [r][128] : ht_W[:,0:128] @ hr + ht_b       (natural)
// gq  [q][256] : gateW[:,128:256] @ h_qr + gateW_b, packed pairs
// wq  [q][64]  : Wqr @ h_qr + Wqr_b              (natural)
// ---------------------------------------------------------------------------
__global__ __launch_bounds__(256) void table_kernel(
    const float* __restrict__ rela, const int* __restrict__ q_rel,
    const float* __restrict__ gateW, const float* __restrict__ gateW_b,
    const float* __restrict__ WrW, const float* __restrict__ WqrW,
    const float* __restrict__ Wqr_b, const float* __restrict__ htW,
    const float* __restrict__ ht_b,
    float* __restrict__ grhr, float* __restrict__ gq,
    float* __restrict__ whr, float* __restrict__ wq,
    float* __restrict__ thr, int vocab)
{
    __shared__ float x[128];
    int b = blockIdx.x, t = threadIdx.x;
    bool isRel = b < vocab;
    int src = isRel ? b : q_rel[b - vocab];
    if (t < 128) x[t] = rela[src * 128 + t];
    __syncthreads();
    const float4* x4 = (const float4*)x;
    {
        const float4* wrow = (const float4*)(gateW + t * 384 + (isRel ? 0 : 128));
        float acc = isRel ? 0.0f : gateW_b[t];
#pragma unroll 8
        for (int i = 0; i < 32; i++) acc += dot4(wrow[i], x4[i]);
        float* dst = isRel ? (grhr + b * 256) : (gq + (b - vocab) * 256);
        dst[2 * (t & 127) + (t >> 7)] = acc;   // row t: <128 update, >=128 reset
    }
    if (isRel) {
        if (t < 192) {
            bool isWr = t < 64;
            int i = isWr ? t : (t - 64);
            const float4* wrow = (const float4*)(isWr ? (WrW + i * 128) : (htW + i * 256));
            float acc = isWr ? 0.0f : ht_b[i];
#pragma unroll 8
            for (int q = 0; q < 32; q++) acc += dot4(wrow[q], x4[q]);
            if (isWr) whr[b * 64 + i] = acc;
            else      thr[b * 128 + i] = acc;
        }
    } else {
        if (t < 64) {
            const float4* wrow = (const float4*)(WqrW + t * 128);
            float acc = Wqr_b[t];
#pragma unroll 8
            for (int q = 0; q < 32; q++) acc += dot4(wrow[q], x4[q]);
            wq[(b - vocab) * 64 + t] = acc;
        }
    }
}

// ---------------------------------------------------------------------------
// Kernel B: per-node precompute.
// gate_hs[n][256] bf16 : gateW[:,256:384] @ hidden[n], packed (u_d, r_d) pairs
// ws_hs  [n][64]  bf16 : Ws @ hidden[n]   (natural)
// hsb    [n][128] bf16 : hidden[n] rounded to bf16 (natural)
// ---------------------------------------------------------------------------
__global__ __launch_bounds__(256) void node_kernel(
    const float* __restrict__ hidden, const float* __restrict__ gateW,
    const float* __restrict__ WsW,
    ushort_t* __restrict__ gate_hs, ushort_t* __restrict__ ws_hs,
    ushort_t* __restrict__ hsb, int nNode)
{
    __shared__ float xl[16 * 132];
    __shared__ float wl[64 * 132];
    int t = threadIdx.x;
    int nloc = t >> 4, rr = t & 15;
    int nbase = blockIdx.x * 16;
    for (int idx = t; idx < 2048; idx += 256) {
        int nn = idx >> 7, j = idx & 127;
        int node = nbase + nn;
        float v = (node < nNode) ? hidden[node * 128 + j] : 0.0f;
        xl[nn * 132 + j] = v;
        if (node < nNode) hsb[(size_t)node * 128 + j] = f2bf(v);
    }
    const float4* xv = (const float4*)(xl + nloc * 132);
    int node = nbase + nloc;
    for (int tile = 0; tile < 5; tile++) {
        __syncthreads();
        for (int idx = t; idx < 8192; idx += 256) {
            int row = idx >> 7, j = idx & 127;
            wl[row * 132 + j] = (tile < 4) ? gateW[(tile * 64 + row) * 384 + 256 + j]
                                           : WsW[row * 128 + j];
        }
        __syncthreads();
        float a0 = 0, a1 = 0, a2 = 0, a3 = 0;
#pragma unroll 4
        for (int q = 0; q < 32; q++) {
            float4 xq = xv[q];
            float4 w0 = *(const float4*)(wl + (rr)*132 + q * 4);
            float4 w1 = *(const float4*)(wl + (rr + 16) * 132 + q * 4);
            float4 w2 = *(const float4*)(wl + (rr + 32) * 132 + q * 4);
            float4 w3 = *(const float4*)(wl + (rr + 48) * 132 + q * 4);
            a0 += dot4(w0, xq); a1 += dot4(w1, xq);
            a2 += dot4(w2, xq); a3 += dot4(w3, xq);
        }
        if (node < nNode) {
            if (tile < 4) {
                ushort_t* dst = gate_hs + (size_t)node * 256;
                int R0 = tile * 64 + rr;
                dst[2 * (R0 & 127) + (R0 >> 7)] = f2bf(a0);
                int R1 = R0 + 16;
                dst[2 * (R1 & 127) + (R1 >> 7)] = f2bf(a1);
                int R2 = R0 + 32;
                dst[2 * (R2 & 127) + (R2 >> 7)] = f2bf(a2);
                int R3 = R0 + 48;
                dst[2 * (R3 & 127) + (R3 >> 7)] = f2bf(a3);
            } else {
                ushort_t* dst = ws_hs + (size_t)node * 64;
                dst[rr] = f2bf(a0); dst[rr + 16] = f2bf(a1);
                dst[rr + 32] = f2bf(a2); dst[rr + 48] = f2bf(a3);
            }
        }
    }
}

// ---------------------------------------------------------------------------
// Edge kernel: 64 edges/block, 4 waves. Wave w owns output dims [32w, 32w+32).
// Phase 1: lane l handles dims 2l,2l+1 of its wave's 16 edges:
//   gates via packed tables, x=reset*hs -> xb (bf16, XOR-swizzled),
//   (A,B)=(sga*(1-u)*h, sga*u) -> ab (bf16 pair, XOR-swizzled), attn alpha.
// Phase 2: MFMA 16x16x32 bf16: C[64 edges][32 dims] = xb @ W2^T (W2 frags in VGPRs).
// Epilogue: cand=tanh(C+thr[rel]), val=A+B*cand, atomicAdd agg.
// ---------------------------------------------------------------------------
__global__ __launch_bounds__(256, 3) void edge_kernel(
    const int* __restrict__ edges, int nEdge,
    const float* __restrict__ grhr, const float* __restrict__ gq,
    const float* __restrict__ whr, const float* __restrict__ wq,
    const float* __restrict__ thr,
    const ushort_t* __restrict__ gate_hs, const ushort_t* __restrict__ ws_hs,
    const ushort_t* __restrict__ hsb,
    const float* __restrict__ walpha, const float* __restrict__ htW,
    float* __restrict__ agg, float* __restrict__ deg)
{
    __shared__ ushort_t xb[64 * 128];   // 16 KB, bf16 x, swz ^((e&7)<<4) on bytes
    __shared__ unsigned ab[64 * 128];   // 32 KB, (A,B) bf16 pair, swz ^((e&1)<<6)
    __shared__ int relL[64];
    __shared__ int objL[64];

    int t = threadIdx.x, w = t >> 6, l = t & 63;
    int lm = l & 15, lh = l >> 4;
    int n0 = w * 32;

    // --- B fragments (W2 = htW[:,128:256] bf16) held in VGPRs, loaded once ---
    short8 bfr[2][4];
#pragma unroll
    for (int nt = 0; nt < 2; nt++)
#pragma unroll
        for (int kt = 0; kt < 4; kt++) {
            const float* src = htW + (size_t)(n0 + nt * 16 + lm) * 256 + 128 + kt * 32 + lh * 8;
            float4 f0 = *(const float4*)src;
            float4 f1 = *(const float4*)(src + 4);
            union { unsigned u[4]; short8 s; } tmp;
            tmp.u[0] = cvt_pk(f0.x, f0.y); tmp.u[1] = cvt_pk(f0.z, f0.w);
            tmp.u[2] = cvt_pk(f1.x, f1.y); tmp.u[3] = cvt_pk(f1.z, f1.w);
            bfr[nt][kt] = tmp.s;
        }
    float wal = walpha[l];

    // --- Phase 1: 16 edges per wave ---
    int ebase = blockIdx.x * 64;
#pragma unroll 4
    for (int i = 0; i < 16; i++) {
        int e = w * 16 + i;
        int eid = ebase + e;
        bool valid = eid < nEdge;
        const int* er = edges + (size_t)(valid ? eid : 0) * 7;
        int ridx = er[0], rel = er[2], sub = er[4], obj = er[5];
        ushort4 gp = *(const ushort4*)(gate_hs + (size_t)sub * 256 + 4 * l);
        float4 ga = *(const float4*)(grhr + (size_t)rel * 256 + 4 * l);
        float4 gb = *(const float4*)(gq + (size_t)ridx * 256 + 4 * l);
        unsigned hp = *(const unsigned*)(hsb + (size_t)sub * 128 + 2 * l);
        float h0 = bf2f((ushort_t)(hp & 0xffffu));
        float h1 = bf2f((ushort_t)(hp >> 16));
        float u0 = sigm(ga.x + gb.x + bf2f(gp.x));
        float r0 = sigm(ga.y + gb.y + bf2f(gp.y));
        float u1 = sigm(ga.z + gb.z + bf2f(gp.z));
        float r1 = sigm(ga.w + gb.w + bf2f(gp.w));
        // attention (64 dims = 64 lanes)
        float aa = bf2f(ws_hs[(size_t)sub * 64 + l]) + whr[rel * 64 + l] + wq[ridx * 64 + l];
        aa = (aa > 0.0f) ? aa : 0.01f * aa;
        float v = aa * wal;
#pragma unroll
        for (int o = 32; o > 0; o >>= 1) v += __shfl_xor(v, o, 64);
        float sga = sigm(v);
        // x = reset*hs -> xb (swizzled)
        unsigned xw = cvt_pk(r0 * h0, r1 * h1);
        *(unsigned*)((char*)xb + ((e * 256 + 4 * l) ^ ((e & 7) << 4))) = xw;
        // (A,B) pair -> ab (swizzled)
        float A0 = sga * (1.0f - u0) * h0;
        float A1 = sga * (1.0f - u1) * h1;
        uint2 abp;
        abp.x = cvt_pk(A0, sga * u0);
        abp.y = cvt_pk(A1, sga * u1);
        *(uint2*)((char*)ab + ((e * 512 + 8 * l) ^ ((e & 1) << 6))) = abp;
        if (l == 0) {
            relL[e] = rel;
            objL[e] = valid ? obj : -1;
            if (valid) atomicAdd(deg + obj, 1.0f);
        }
    }
    __syncthreads();

    // --- Phase 2: A fragments + MFMA ---
    short8 afr[4][4];
#pragma unroll
    for (int mt = 0; mt < 4; mt++)
#pragma unroll
        for (int kt = 0; kt < 4; kt++) {
            int e = mt * 16 + lm;
            afr[mt][kt] = *(const short8*)((const char*)xb +
                ((e * 256 + kt * 64 + lh * 16) ^ ((e & 7) << 4)));
        }
    f32x4 acc[4][2];
#pragma unroll
    for (int mt = 0; mt < 4; mt++)
#pragma unroll
        for (int nt = 0; nt < 2; nt++) acc[mt][nt] = (f32x4){0.f, 0.f, 0.f, 0.f};
#pragma unroll
    for (int kt = 0; kt < 4; kt++)
#pragma unroll
        for (int mt = 0; mt < 4; mt++)
#pragma unroll
            for (int nt = 0; nt < 2; nt++)
                acc[mt][nt] = __builtin_amdgcn_mfma_f32_16x16x32_bf16(
                    afr[mt][kt], bfr[nt][kt], acc[mt][nt], 0, 0, 0);

    // --- Epilogue: tanh, message, atomics ---
#pragma unroll
    for (int mt = 0; mt < 4; mt++)
#pragma unroll
        for (int nt = 0; nt < 2; nt++) {
            int d = n0 + nt * 16 + lm;
#pragma unroll
            for (int r = 0; r < 4; r++) {
                int e = mt * 16 + lh * 4 + r;
                int rel = relL[e];
                int obj = objL[e];
                float th = thr[rel * 128 + d];
                float cand = tanh_fast(acc[mt][nt][r] + th);
                unsigned abw = *(const unsigned*)((const char*)ab +
                    ((e * 512 + 4 * d) ^ ((e & 1) << 6)));
                float val = bf2f((ushort_t)(abw & 0xffffu)) +
                            bf2f((ushort_t)(abw >> 16)) * cand;
                if (obj >= 0) atomicAdd(agg + (size_t)obj * 128 + d, val);
            }
        }
}

// ---------------------------------------------------------------------------
// Final: out[n] = (agg[n]/sqrt(deg[n]+1e-4)) @ Wh.T, in place over d_out.
// ---------------------------------------------------------------------------
__global__ __launch_bounds__(256) void final_kernel(
    const float* __restrict__ WhW, const float* __restrict__ deg,
    float* __restrict__ agg, int nNode)
{
    __shared__ unsigned whp[64 * 128];  // [jj][col] = (Wh[col][2jj], Wh[col][2jj+1]) bf16
    __shared__ float xr[2][132];
    int t = threadIdx.x;
    for (int idx = t; idx < 8192; idx += 256) {
        int col = idx >> 6, jj = idx & 63;
        unsigned lo = (unsigned)f2bf(WhW[col * 128 + 2 * jj]);
        unsigned hi = (unsigned)f2bf(WhW[col * 128 + 2 * jj + 1]);
        whp[jj * 128 + col] = lo | (hi << 16);
    }
    int nl = t >> 7, col = t & 127;
    int nPairs = (nNode + 1) >> 1;
    for (int p = blockIdx.x; p < nPairs; p += gridDim.x) {
        int n = p * 2 + nl;
        bool valid = n < nNode;
        __syncthreads();
        if (valid) {
            float d = deg[n];
            float r = 1.0f / sqrtf(d + 1e-4f);
            xr[nl][col] = agg[(size_t)n * 128 + col] * r;
        }
        __syncthreads();
        float acc = 0.0f;
#pragma unroll 8
        for (int jj = 0; jj < 64; jj++) {
            unsigned wp = whp[jj * 128 + col];
            float2 xa = *(const float2*)&xr[nl][2 * jj];
            acc = fmaf(__uint_as_float(wp << 16), xa.x, acc);
            acc = fmaf(__uint_as_float(wp & 0xffff0000u), xa.y, acc);
        }
        if (valid) agg[(size_t)n * 128 + col] = acc;
    }
}

extern "C" void kernel_launch(void* const* d_in, const int* in_sizes, int n_in,
                              void* d_out, int out_size, void* d_ws, size_t ws_size,
                              hipStream_t stream)
{
    const int*   q_rel   = (const int*)d_in[1];
    const float* hidden  = (const float*)d_in[2];
    const int*   edges   = (const int*)d_in[3];
    const float* rela    = (const float*)d_in[5];
    const float* WsW     = (const float*)d_in[6];
    const float* WrW     = (const float*)d_in[7];
    const float* WqrW    = (const float*)d_in[8];
    const float* Wqr_b   = (const float*)d_in[9];
    const float* walpha  = (const float*)d_in[10];
    const float* gateW   = (const float*)d_in[11];
    const float* gateW_b = (const float*)d_in[12];
    const float* htW     = (const float*)d_in[13];
    const float* ht_b    = (const float*)d_in[14];
    const float* WhW     = (const float*)d_in[15];

    int nNode  = in_sizes[2] / 128;
    int nEdge  = in_sizes[3] / 7;
    int vocab  = in_sizes[5] / 128;
    int nQuery = in_sizes[1];

    char* ws = (char*)d_ws;
    size_t off = 0;
    auto alloc = [&](size_t bytes) { size_t o = off; off += (bytes + 255) & ~(size_t)255; return o; };
    float*    degp    = (float*)(ws + alloc((size_t)nNode * 4));
    float*    grhr    = (float*)(ws + alloc((size_t)vocab * 256 * 4));
    float*    whr     = (float*)(ws + alloc((size_t)vocab * 64 * 4));
    float*    thr     = (float*)(ws + alloc((size_t)vocab * 128 * 4));
    float*    gq      = (float*)(ws + alloc((size_t)nQuery * 256 * 4));
    float*    wq      = (float*)(ws + alloc((size_t)nQuery * 64 * 4));
    ushort_t* gate_hs = (ushort_t*)(ws + alloc((size_t)nNode * 256 * 2));
    ushort_t* ws_hs   = (ushort_t*)(ws + alloc((size_t)nNode * 64 * 2));
    ushort_t* hsb     = (ushort_t*)(ws + alloc((size_t)nNode * 128 * 2));
    if (off > ws_size) return;  // workspace too small -> zero output (diagnostic)

    float* agg = (float*)d_out;
    hipMemsetAsync(agg, 0, (size_t)nNode * 128 * 4, stream);
    hipMemsetAsync(degp, 0, (size_t)nNode * 4, stream);

    table_kernel<<<vocab + nQuery, 256, 0, stream>>>(
        rela, q_rel, gateW, gateW_b, WrW, WqrW, Wqr_b, htW, ht_b,
        grhr, gq, whr, wq, thr, vocab);

    int ngrp = (nNode + 15) / 16;
    node_kernel<<<ngrp, 256, 0, stream>>>(hidden, gateW, WsW, gate_hs, ws_hs, hsb, nNode);

    int eblocks = (nEdge + 63) / 64;
    edge_kernel<<<eblocks, 256, 0, stream>>>(
        edges, nEdge, grhr, gq, whr, wq, thr,
        gate_hs, ws_hs, hsb, walpha, htW, agg, degp);

    int pairs = (nNode + 1) / 2;
    int fgrid = pairs < 2048 ? pairs : 2048;
    final_kernel<<<fgrid, 256, 0, stream>>>(WhW, degp, agg, nNode);
}

// Round 3
// 488.532 us; speedup vs baseline: 1.5982x; 1.3876x over previous
//
#include <hip/hip_runtime.h>

typedef unsigned short ushort_t;
typedef __attribute__((ext_vector_type(8))) short short8;
typedef __attribute__((ext_vector_type(4))) float f32x4;

#define DEV __device__ __forceinline__

DEV float sigm(float x) { return 1.0f / (1.0f + __expf(-x)); }
DEV float tanh_fast(float x) { return 1.0f - 2.0f / (__expf(2.0f * x) + 1.0f); }
DEV ushort_t f2bf(float v) {
    unsigned u = __float_as_uint(v);
    unsigned r = (u + 0x7fffu + ((u >> 16) & 1u)) >> 16;
    return (ushort_t)r;
}
DEV float bf2f(ushort_t h) { return __uint_as_float(((unsigned)h) << 16); }
DEV unsigned cvt_pk(float lo, float hi) {
    unsigned r;
    asm("v_cvt_pk_bf16_f32 %0, %1, %2" : "=v"(r) : "v"(lo), "v"(hi));
    return r;
}
DEV float dot4(float4 a, float4 b) {
    return fmaf(a.x, b.x, fmaf(a.y, b.y, fmaf(a.z, b.z, a.w * b.w)));
}

// ---------------------------------------------------------------------------
// Kernel A: per-rel and per-query tables (small; VALU is fine here).
// grhr[r][256] : gateW[:,0:128] @ hr, packed (update_d, reset_d): slot 2d+{0,1}
// whr [r][64]  : Wr @ hr
// thr [r][128] : ht_W[:,0:128] @ hr + ht_b
// gq  [q][256] : gateW[:,128:256] @ h_qr + gateW_b, packed pairs
// wq  [q][64]  : Wqr @ h_qr + Wqr_b
// ---------------------------------------------------------------------------
__global__ __launch_bounds__(256) void table_kernel(
    const float* __restrict__ rela, const int* __restrict__ q_rel,
    const float* __restrict__ gateW, const float* __restrict__ gateW_b,
    const float* __restrict__ WrW, const float* __restrict__ WqrW,
    const float* __restrict__ Wqr_b, const float* __restrict__ htW,
    const float* __restrict__ ht_b,
    float* __restrict__ grhr, float* __restrict__ gq,
    float* __restrict__ whr, float* __restrict__ wq,
    float* __restrict__ thr, int vocab)
{
    __shared__ float x[128];
    int b = blockIdx.x, t = threadIdx.x;
    bool isRel = b < vocab;
    int src = isRel ? b : q_rel[b - vocab];
    if (t < 128) x[t] = rela[src * 128 + t];
    __syncthreads();
    const float4* x4 = (const float4*)x;
    {
        const float4* wrow = (const float4*)(gateW + t * 384 + (isRel ? 0 : 128));
        float acc = isRel ? 0.0f : gateW_b[t];
#pragma unroll 8
        for (int i = 0; i < 32; i++) acc += dot4(wrow[i], x4[i]);
        float* dst = isRel ? (grhr + b * 256) : (gq + (b - vocab) * 256);
        dst[2 * (t & 127) + (t >> 7)] = acc;
    }
    if (isRel) {
        if (t < 192) {
            bool isWr = t < 64;
            int i = isWr ? t : (t - 64);
            const float4* wrow = (const float4*)(isWr ? (WrW + i * 128) : (htW + i * 256));
            float acc = isWr ? 0.0f : ht_b[i];
#pragma unroll 8
            for (int q = 0; q < 32; q++) acc += dot4(wrow[q], x4[q]);
            if (isWr) whr[b * 64 + i] = acc;
            else      thr[b * 128 + i] = acc;
        }
    } else {
        if (t < 64) {
            const float4* wrow = (const float4*)(WqrW + t * 128);
            float acc = Wqr_b[t];
#pragma unroll 8
            for (int q = 0; q < 32; q++) acc += dot4(wrow[q], x4[q]);
            wq[(b - vocab) * 64 + t] = acc;
        }
    }
}

// ---------------------------------------------------------------------------
// Kernel B (MFMA): per-node precompute.
// Stacked weight rows 0..255 = gateW[:,256:384], rows 256..319 = Ws.
// C[32 nodes][320] per block; wave w owns rows [80w, 80w+80) (5 N-tiles).
// gate_hs[n][256] bf16 packed (u_d, r_d); ws_hs[n][64] bf16; hsb[n][128] bf16.
// ---------------------------------------------------------------------------
__global__ __launch_bounds__(256) void node_kernel(
    const float* __restrict__ hidden, const float* __restrict__ gateW,
    const float* __restrict__ WsW,
    ushort_t* __restrict__ gate_hs, ushort_t* __restrict__ ws_hs,
    ushort_t* __restrict__ hsb, int nNode)
{
    __shared__ char a_lds[32 * 256];   // 8 KB: [node][128 bf16], swz ^((row&7)<<4)
    int t = threadIdx.x, w = t >> 6, l = t & 63;
    int lm = l & 15, lh = l >> 4;
    int nbase = blockIdx.x * 32;

    // Stage hidden rows -> bf16 LDS (+ hsb global copy)
    for (int idx = t; idx < 1024; idx += 256) {
        int row = idx >> 5, c4 = idx & 31;
        int node = nbase + row;
        float4 v = (node < nNode) ? ((const float4*)hidden)[(size_t)node * 32 + c4]
                                  : float4{0.f, 0.f, 0.f, 0.f};
        uint2 p;
        p.x = cvt_pk(v.x, v.y);
        p.y = cvt_pk(v.z, v.w);
        *(uint2*)(a_lds + ((row * 256 + c4 * 8) ^ ((row & 7) << 4))) = p;
        if (node < nNode) *(uint2*)(hsb + (size_t)node * 128 + c4 * 4) = p;
    }

    // B fragments: 5 N-tiles x 4 K-tiles, from global f32 (L2-resident)
    short8 bfr[5][4];
#pragma unroll
    for (int nt = 0; nt < 5; nt++)
#pragma unroll
        for (int kt = 0; kt < 4; kt++) {
            int row = w * 80 + nt * 16 + lm;
            const float* src = (row < 256)
                ? gateW + (size_t)row * 384 + 256 + kt * 32 + lh * 8
                : WsW + (size_t)(row - 256) * 128 + kt * 32 + lh * 8;
            float4 f0 = *(const float4*)src;
            float4 f1 = *(const float4*)(src + 4);
            union { unsigned u[4]; short8 s; } tmp;
            tmp.u[0] = cvt_pk(f0.x, f0.y); tmp.u[1] = cvt_pk(f0.z, f0.w);
            tmp.u[2] = cvt_pk(f1.x, f1.y); tmp.u[3] = cvt_pk(f1.z, f1.w);
            bfr[nt][kt] = tmp.s;
        }
    __syncthreads();

    short8 afr[2][4];
#pragma unroll
    for (int mt = 0; mt < 2; mt++)
#pragma unroll
        for (int kt = 0; kt < 4; kt++) {
            int row = mt * 16 + lm;
            afr[mt][kt] = *(const short8*)(a_lds +
                ((row * 256 + kt * 64 + lh * 16) ^ ((row & 7) << 4)));
        }
    f32x4 acc[2][5];
#pragma unroll
    for (int mt = 0; mt < 2; mt++)
#pragma unroll
        for (int nt = 0; nt < 5; nt++) acc[mt][nt] = (f32x4){0.f, 0.f, 0.f, 0.f};
#pragma unroll
    for (int kt = 0; kt < 4; kt++)
#pragma unroll
        for (int mt = 0; mt < 2; mt++)
#pragma unroll
            for (int nt = 0; nt < 5; nt++)
                acc[mt][nt] = __builtin_amdgcn_mfma_f32_16x16x32_bf16(
                    afr[mt][kt], bfr[nt][kt], acc[mt][nt], 0, 0, 0);

#pragma unroll
    for (int mt = 0; mt < 2; mt++)
#pragma unroll
        for (int nt = 0; nt < 5; nt++) {
            int wrow = w * 80 + nt * 16 + lm;
#pragma unroll
            for (int r = 0; r < 4; r++) {
                int node = nbase + mt * 16 + lh * 4 + r;
                if (node < nNode) {
                    ushort_t v = f2bf(acc[mt][nt][r]);
                    if (wrow < 256)
                        gate_hs[(size_t)node * 256 + 2 * (wrow & 127) + (wrow >> 7)] = v;
                    else
                        ws_hs[(size_t)node * 64 + wrow - 256] = v;
                }
            }
        }
}

// ---------------------------------------------------------------------------
// deg kernel: one thread per edge, all lanes active.
// ---------------------------------------------------------------------------
__global__ __launch_bounds__(256) void deg_kernel(
    const int* __restrict__ edges, int nEdge, float* __restrict__ deg)
{
    int i = blockIdx.x * 256 + threadIdx.x;
    if (i < nEdge) atomicAdd(deg + edges[(size_t)i * 7 + 5], 1.0f);
}

// ---------------------------------------------------------------------------
// Edge kernel: 32 edges/block, 4 waves; wave w owns output dims [32w, 32w+32).
// LDS 24.9 KB -> 6 blocks/CU (75% occupancy).
// ---------------------------------------------------------------------------
__global__ __launch_bounds__(256, 6) void edge_kernel(
    const int* __restrict__ edges, int nEdge,
    const float* __restrict__ grhr, const float* __restrict__ gq,
    const float* __restrict__ whr, const float* __restrict__ wq,
    const float* __restrict__ thr,
    const ushort_t* __restrict__ gate_hs, const ushort_t* __restrict__ ws_hs,
    const ushort_t* __restrict__ hsb,
    const float* __restrict__ walpha, const float* __restrict__ htW,
    float* __restrict__ agg)
{
    __shared__ ushort_t xb[32 * 128];   // 8 KB, x bf16, swz ^((e&7)<<4)
    __shared__ unsigned ab[32 * 128];   // 16 KB, (A,B) bf16 pair, swz ^(((e>>2)&3)<<6)
    __shared__ int eds[32 * 7];         // staged edge rows

    int t = threadIdx.x, w = t >> 6, l = t & 63;
    int lm = l & 15, lh = l >> 4;
    int n0 = w * 32;
    int ebase = blockIdx.x * 32;

    for (int idx = t; idx < 224; idx += 256) {
        int gi = ebase * 7 + idx;
        eds[idx] = (gi < nEdge * 7) ? edges[gi] : 0;
    }

    // B fragments (W2 = htW[:,128:256] bf16) in VGPRs
    short8 bfr[2][4];
#pragma unroll
    for (int nt = 0; nt < 2; nt++)
#pragma unroll
        for (int kt = 0; kt < 4; kt++) {
            const float* src = htW + (size_t)(n0 + nt * 16 + lm) * 256 + 128 + kt * 32 + lh * 8;
            float4 f0 = *(const float4*)src;
            float4 f1 = *(const float4*)(src + 4);
            union { unsigned u[4]; short8 s; } tmp;
            tmp.u[0] = cvt_pk(f0.x, f0.y); tmp.u[1] = cvt_pk(f0.z, f0.w);
            tmp.u[2] = cvt_pk(f1.x, f1.y); tmp.u[3] = cvt_pk(f1.z, f1.w);
            bfr[nt][kt] = tmp.s;
        }
    float wal = walpha[l];
    __syncthreads();   // eds ready

    // --- Phase 1: 8 edges per wave ---
#pragma unroll 4
    for (int i = 0; i < 8; i++) {
        int e = w * 8 + i;
        int ridx = eds[e * 7 + 0], rel = eds[e * 7 + 2], sub = eds[e * 7 + 4];
        ushort4 gp = *(const ushort4*)(gate_hs + (size_t)sub * 256 + 4 * l);
        float4 ga = *(const float4*)(grhr + (size_t)rel * 256 + 4 * l);
        float4 gb = *(const float4*)(gq + (size_t)ridx * 256 + 4 * l);
        unsigned hp = *(const unsigned*)(hsb + (size_t)sub * 128 + 2 * l);
        float h0 = bf2f((ushort_t)(hp & 0xffffu));
        float h1 = bf2f((ushort_t)(hp >> 16));
        float u0 = sigm(ga.x + gb.x + bf2f(gp.x));
        float r0 = sigm(ga.y + gb.y + bf2f(gp.y));
        float u1 = sigm(ga.z + gb.z + bf2f(gp.z));
        float r1 = sigm(ga.w + gb.w + bf2f(gp.w));
        float aa = bf2f(ws_hs[(size_t)sub * 64 + l]) + whr[rel * 64 + l] + wq[ridx * 64 + l];
        aa = (aa > 0.0f) ? aa : 0.01f * aa;
        float v = aa * wal;
#pragma unroll
        for (int o = 32; o > 0; o >>= 1) v += __shfl_xor(v, o, 64);
        float sga = sigm(v);
        unsigned xw = cvt_pk(r0 * h0, r1 * h1);
        *(unsigned*)((char*)xb + ((e * 256 + 4 * l) ^ ((e & 7) << 4))) = xw;
        float A0 = sga * (1.0f - u0) * h0;
        float A1 = sga * (1.0f - u1) * h1;
        uint2 abp;
        abp.x = cvt_pk(A0, sga * u0);
        abp.y = cvt_pk(A1, sga * u1);
        *(uint2*)((char*)ab + ((e * 512 + 8 * l) ^ (((e >> 2) & 3) << 6))) = abp;
    }
    __syncthreads();

    // --- Phase 2: MFMA C[32 edges][32 dims] ---
    short8 afr[2][4];
#pragma unroll
    for (int mt = 0; mt < 2; mt++)
#pragma unroll
        for (int kt = 0; kt < 4; kt++) {
            int e = mt * 16 + lm;
            afr[mt][kt] = *(const short8*)((const char*)xb +
                ((e * 256 + kt * 64 + lh * 16) ^ ((e & 7) << 4)));
        }
    f32x4 acc[2][2];
#pragma unroll
    for (int mt = 0; mt < 2; mt++)
#pragma unroll
        for (int nt = 0; nt < 2; nt++) acc[mt][nt] = (f32x4){0.f, 0.f, 0.f, 0.f};
#pragma unroll
    for (int kt = 0; kt < 4; kt++)
#pragma unroll
        for (int mt = 0; mt < 2; mt++)
#pragma unroll
            for (int nt = 0; nt < 2; nt++)
                acc[mt][nt] = __builtin_amdgcn_mfma_f32_16x16x32_bf16(
                    afr[mt][kt], bfr[nt][kt], acc[mt][nt], 0, 0, 0);

    // --- Epilogue ---
#pragma unroll
    for (int mt = 0; mt < 2; mt++)
#pragma unroll
        for (int nt = 0; nt < 2; nt++) {
            int d = n0 + nt * 16 + lm;
#pragma unroll
            for (int r = 0; r < 4; r++) {
                int e = mt * 16 + lh * 4 + r;
                bool valid = (ebase + e) < nEdge;
                int rel = eds[e * 7 + 2];
                int obj = eds[e * 7 + 5];
                float th = thr[rel * 128 + d];
                float cand = tanh_fast(acc[mt][nt][r] + th);
                unsigned abw = *(const unsigned*)((const char*)ab +
                    ((e * 512 + 4 * d) ^ (((e >> 2) & 3) << 6)));
                float val = bf2f((ushort_t)(abw & 0xffffu)) +
                            bf2f((ushort_t)(abw >> 16)) * cand;
                if (valid) atomicAdd(agg + (size_t)obj * 128 + d, val);
            }
        }
}

// ---------------------------------------------------------------------------
// Final (MFMA): out[n] = (agg[n]/sqrt(deg[n]+1e-4)) @ Wh.T, in place.
// 64 nodes/block, 4 waves; wave w owns cols [32w, 32w+32).
// ---------------------------------------------------------------------------
__global__ __launch_bounds__(256) void final_kernel(
    const float* __restrict__ WhW, const float* __restrict__ deg,
    float* __restrict__ agg, int nNode)
{
    __shared__ char y_lds[64 * 256];  // 16 KB: [node][128 bf16], swz ^((row&7)<<4)
    int t = threadIdx.x, w = t >> 6, l = t & 63;
    int lm = l & 15, lh = l >> 4;
    int nbase = blockIdx.x * 64;

    // B fragments from Wh (f32 -> bf16), L2-resident
    short8 bfr[2][4];
#pragma unroll
    for (int nt = 0; nt < 2; nt++)
#pragma unroll
        for (int kt = 0; kt < 4; kt++) {
            const float* src = WhW + (size_t)(w * 32 + nt * 16 + lm) * 128 + kt * 32 + lh * 8;
            float4 f0 = *(const float4*)src;
            float4 f1 = *(const float4*)(src + 4);
            union { unsigned u[4]; short8 s; } tmp;
            tmp.u[0] = cvt_pk(f0.x, f0.y); tmp.u[1] = cvt_pk(f0.z, f0.w);
            tmp.u[2] = cvt_pk(f1.x, f1.y); tmp.u[3] = cvt_pk(f1.z, f1.w);
            bfr[nt][kt] = tmp.s;
        }

    // Stage Y = agg * rsqrt(deg+eps) -> bf16 LDS
    for (int idx = t; idx < 2048; idx += 256) {
        int row = idx >> 5, c4 = idx & 31;
        int node = nbase + row;
        uint2 p = {0u, 0u};
        if (node < nNode) {
            float4 v = ((const float4*)agg)[(size_t)node * 32 + c4];
            float r = 1.0f / sqrtf(deg[node] + 1e-4f);
            p.x = cvt_pk(v.x * r, v.y * r);
            p.y = cvt_pk(v.z * r, v.w * r);
        }
        *(uint2*)(y_lds + ((row * 256 + c4 * 8) ^ ((row & 7) << 4))) = p;
    }
    __syncthreads();

    short8 afr[4][4];
#pragma unroll
    for (int mt = 0; mt < 4; mt++)
#pragma unroll
        for (int kt = 0; kt < 4; kt++) {
            int row = mt * 16 + lm;
            afr[mt][kt] = *(const short8*)(y_lds +
                ((row * 256 + kt * 64 + lh * 16) ^ ((row & 7) << 4)));
        }
    f32x4 acc[4][2];
#pragma unroll
    for (int mt = 0; mt < 4; mt++)
#pragma unroll
        for (int nt = 0; nt < 2; nt++) acc[mt][nt] = (f32x4){0.f, 0.f, 0.f, 0.f};
#pragma unroll
    for (int kt = 0; kt < 4; kt++)
#pragma unroll
        for (int mt = 0; mt < 4; mt++)
#pragma unroll
            for (int nt = 0; nt < 2; nt++)
                acc[mt][nt] = __builtin_amdgcn_mfma_f32_16x16x32_bf16(
                    afr[mt][kt], bfr[nt][kt], acc[mt][nt], 0, 0, 0);

#pragma unroll
    for (int mt = 0; mt < 4; mt++)
#pragma unroll
        for (int nt = 0; nt < 2; nt++) {
            int col = w * 32 + nt * 16 + lm;
#pragma unroll
            for (int r = 0; r < 4; r++) {
                int node = nbase + mt * 16 + lh * 4 + r;
                if (node < nNode) agg[(size_t)node * 128 + col] = acc[mt][nt][r];
            }
        }
}

extern "C" void kernel_launch(void* const* d_in, const int* in_sizes, int n_in,
                              void* d_out, int out_size, void* d_ws, size_t ws_size,
                              hipStream_t stream)
{
    const int*   q_rel   = (const int*)d_in[1];
    const float* hidden  = (const float*)d_in[2];
    const int*   edges   = (const int*)d_in[3];
    const float* rela    = (const float*)d_in[5];
    const float* WsW     = (const float*)d_in[6];
    const float* WrW     = (const float*)d_in[7];
    const float* WqrW    = (const float*)d_in[8];
    const float* Wqr_b   = (const float*)d_in[9];
    const float* walpha  = (const float*)d_in[10];
    const float* gateW   = (const float*)d_in[11];
    const float* gateW_b = (const float*)d_in[12];
    const float* htW     = (const float*)d_in[13];
    const float* ht_b    = (const float*)d_in[14];
    const float* WhW     = (const float*)d_in[15];

    int nNode  = in_sizes[2] / 128;
    int nEdge  = in_sizes[3] / 7;
    int vocab  = in_sizes[5] / 128;
    int nQuery = in_sizes[1];

    char* ws = (char*)d_ws;
    size_t off = 0;
    auto alloc = [&](size_t bytes) { size_t o = off; off += (bytes + 255) & ~(size_t)255; return o; };
    float*    degp    = (float*)(ws + alloc((size_t)nNode * 4));
    float*    grhr    = (float*)(ws + alloc((size_t)vocab * 256 * 4));
    float*    whr     = (float*)(ws + alloc((size_t)vocab * 64 * 4));
    float*    thr     = (float*)(ws + alloc((size_t)vocab * 128 * 4));
    float*    gq      = (float*)(ws + alloc((size_t)nQuery * 256 * 4));
    float*    wq      = (float*)(ws + alloc((size_t)nQuery * 64 * 4));
    ushort_t* gate_hs = (ushort_t*)(ws + alloc((size_t)nNode * 256 * 2));
    ushort_t* ws_hs   = (ushort_t*)(ws + alloc((size_t)nNode * 64 * 2));
    ushort_t* hsb     = (ushort_t*)(ws + alloc((size_t)nNode * 128 * 2));
    if (off > ws_size) return;

    float* agg = (float*)d_out;
    hipMemsetAsync(agg, 0, (size_t)nNode * 128 * 4, stream);
    hipMemsetAsync(degp, 0, (size_t)nNode * 4, stream);

    table_kernel<<<vocab + nQuery, 256, 0, stream>>>(
        rela, q_rel, gateW, gateW_b, WrW, WqrW, Wqr_b, htW, ht_b,
        grhr, gq, whr, wq, thr, vocab);

    int ngrp = (nNode + 31) / 32;
    node_kernel<<<ngrp, 256, 0, stream>>>(hidden, gateW, WsW, gate_hs, ws_hs, hsb, nNode);

    deg_kernel<<<(nEdge + 255) / 256, 256, 0, stream>>>(edges, nEdge, degp);

    int eblocks = (nEdge + 31) / 32;
    edge_kernel<<<eblocks, 256, 0, stream>>>(
        edges, nEdge, grhr, gq, whr, wq, thr,
        gate_hs, ws_hs, hsb, walpha, htW, agg);

    int fblocks = (nNode + 63) / 64;
    final_kernel<<<fblocks, 256, 0, stream>>>(WhW, degp, agg, nNode);
}

// Round 4
// 448.434 us; speedup vs baseline: 1.7411x; 1.0894x over previous
//
#include <hip/hip_runtime.h>

typedef unsigned short ushort_t;
typedef __attribute__((ext_vector_type(8))) short short8;
typedef __attribute__((ext_vector_type(4))) float f32x4;

#define DEV __device__ __forceinline__

DEV float sigm(float x) { return 1.0f / (1.0f + __expf(-x)); }
DEV float tanh_fast(float x) { return 1.0f - 2.0f / (__expf(2.0f * x) + 1.0f); }
DEV ushort_t f2bf(float v) {
    unsigned u = __float_as_uint(v);
    unsigned r = (u + 0x7fffu + ((u >> 16) & 1u)) >> 16;
    return (ushort_t)r;
}
DEV float bf2f(ushort_t h) { return __uint_as_float(((unsigned)h) << 16); }
DEV unsigned cvt_pk(float lo, float hi) {
    unsigned r;
    asm("v_cvt_pk_bf16_f32 %0, %1, %2" : "=v"(r) : "v"(lo), "v"(hi));
    return r;
}
DEV float dot4(float4 a, float4 b) {
    return fmaf(a.x, b.x, fmaf(a.y, b.y, fmaf(a.z, b.z, a.w * b.w)));
}

// ---------------------------------------------------------------------------
// Sorting machinery: counting sort of edges by obj.
// ---------------------------------------------------------------------------
__global__ __launch_bounds__(256) void hist_kernel(
    const int* __restrict__ edges, int nEdge, int* __restrict__ cnt)
{
    int i = blockIdx.x * 256 + threadIdx.x;
    if (i < nEdge) atomicAdd(cnt + edges[(size_t)i * 7 + 5], 1);
}

__global__ __launch_bounds__(256) void scan1_kernel(
    const int* __restrict__ cnt, int n, int* __restrict__ partials)
{
    __shared__ int s[256];
    int t = threadIdx.x;
    int i = blockIdx.x * 256 + t;
    s[t] = (i < n) ? cnt[i] : 0;
    __syncthreads();
    for (int o = 128; o > 0; o >>= 1) {
        if (t < o) s[t] += s[t + o];
        __syncthreads();
    }
    if (t == 0) partials[blockIdx.x] = s[0];
}

__global__ __launch_bounds__(256) void scan2_kernel(
    const int* __restrict__ cnt, int n, const int* __restrict__ partials,
    int nBlk, int* __restrict__ start, int* __restrict__ cursor)
{
    __shared__ int ps[256];
    __shared__ int loc[256];
    int t = threadIdx.x, b = blockIdx.x;
    ps[t] = (t < nBlk) ? partials[t] : 0;
    __syncthreads();
    for (int o = 1; o < 256; o <<= 1) {          // inclusive scan of partials
        int v = (t >= o) ? ps[t - o] : 0;
        __syncthreads();
        ps[t] += v;
        __syncthreads();
    }
    int offset = (b > 0) ? ps[b - 1] : 0;
    int i = b * 256 + t;
    int v = (i < n) ? cnt[i] : 0;
    loc[t] = v;
    __syncthreads();
    for (int o = 1; o < 256; o <<= 1) {          // inclusive scan local
        int x = (t >= o) ? loc[t - o] : 0;
        __syncthreads();
        loc[t] += x;
        __syncthreads();
    }
    if (i < n) {
        int excl = offset + loc[t] - v;
        start[i] = excl;
        cursor[i] = excl;
    }
}

__global__ __launch_bounds__(256) void build_kernel(
    const int* __restrict__ edges, int nEdge, int* __restrict__ cursor,
    int4* __restrict__ sorted)
{
    int i = blockIdx.x * 256 + threadIdx.x;
    if (i < nEdge) {
        const int* er = edges + (size_t)i * 7;
        int obj = er[5];
        int s = atomicAdd(cursor + obj, 1);
        sorted[s] = make_int4(er[0], er[2], er[4], obj);
    }
}

// ---------------------------------------------------------------------------
// Kernel A: per-rel and per-query tables.
// grhr[r][256] : gateW[:,0:128] @ hr, packed (update_d, reset_d): slot 2d+{0,1}
// whr [r][64]  : Wr @ hr
// thr [r][128] : ht_W[:,0:128] @ hr + ht_b
// gq  [q][256] : gateW[:,128:256] @ h_qr + gateW_b, packed pairs
// wq  [q][64]  : Wqr @ h_qr + Wqr_b
// ---------------------------------------------------------------------------
__global__ __launch_bounds__(256) void table_kernel(
    const float* __restrict__ rela, const int* __restrict__ q_rel,
    const float* __restrict__ gateW, const float* __restrict__ gateW_b,
    const float* __restrict__ WrW, const float* __restrict__ WqrW,
    const float* __restrict__ Wqr_b, const float* __restrict__ htW,
    const float* __restrict__ ht_b,
    float* __restrict__ grhr, float* __restrict__ gq,
    float* __restrict__ whr, float* __restrict__ wq,
    float* __restrict__ thr, int vocab)
{
    __shared__ float x[128];
    int b = blockIdx.x, t = threadIdx.x;
    bool isRel = b < vocab;
    int src = isRel ? b : q_rel[b - vocab];
    if (t < 128) x[t] = rela[src * 128 + t];
    __syncthreads();
    const float4* x4 = (const float4*)x;
    {
        const float4* wrow = (const float4*)(gateW + t * 384 + (isRel ? 0 : 128));
        float acc = isRel ? 0.0f : gateW_b[t];
#pragma unroll 8
        for (int i = 0; i < 32; i++) acc += dot4(wrow[i], x4[i]);
        float* dst = isRel ? (grhr + b * 256) : (gq + (b - vocab) * 256);
        dst[2 * (t & 127) + (t >> 7)] = acc;
    }
    if (isRel) {
        if (t < 192) {
            bool isWr = t < 64;
            int i = isWr ? t : (t - 64);
            const float4* wrow = (const float4*)(isWr ? (WrW + i * 128) : (htW + i * 256));
            float acc = isWr ? 0.0f : ht_b[i];
#pragma unroll 8
            for (int q = 0; q < 32; q++) acc += dot4(wrow[q], x4[q]);
            if (isWr) whr[b * 64 + i] = acc;
            else      thr[b * 128 + i] = acc;
        }
    } else {
        if (t < 64) {
            const float4* wrow = (const float4*)(WqrW + t * 128);
            float acc = Wqr_b[t];
#pragma unroll 8
            for (int q = 0; q < 32; q++) acc += dot4(wrow[q], x4[q]);
            wq[(b - vocab) * 64 + t] = acc;
        }
    }
}

// ---------------------------------------------------------------------------
// Kernel B (MFMA): per-node precompute.
// Stacked weight rows 0..255 = gateW[:,256:384], rows 256..319 = Ws.
// gate_hs[n][256] bf16 packed (u_d, r_d); ws_hs[n][64] bf16; hsb[n][128] bf16.
// ---------------------------------------------------------------------------
__global__ __launch_bounds__(256) void node_kernel(
    const float* __restrict__ hidden, const float* __restrict__ gateW,
    const float* __restrict__ WsW,
    ushort_t* __restrict__ gate_hs, ushort_t* __restrict__ ws_hs,
    ushort_t* __restrict__ hsb, int nNode)
{
    __shared__ char a_lds[32 * 256];   // [node][128 bf16], swz ^((row&7)<<4)
    int t = threadIdx.x, w = t >> 6, l = t & 63;
    int lm = l & 15, lh = l >> 4;
    int nbase = blockIdx.x * 32;

    for (int idx = t; idx < 1024; idx += 256) {
        int row = idx >> 5, c4 = idx & 31;
        int node = nbase + row;
        float4 v = (node < nNode) ? ((const float4*)hidden)[(size_t)node * 32 + c4]
                                  : float4{0.f, 0.f, 0.f, 0.f};
        uint2 p;
        p.x = cvt_pk(v.x, v.y);
        p.y = cvt_pk(v.z, v.w);
        *(uint2*)(a_lds + ((row * 256 + c4 * 8) ^ ((row & 7) << 4))) = p;
        if (node < nNode) *(uint2*)(hsb + (size_t)node * 128 + c4 * 4) = p;
    }

    short8 bfr[5][4];
#pragma unroll
    for (int nt = 0; nt < 5; nt++)
#pragma unroll
        for (int kt = 0; kt < 4; kt++) {
            int row = w * 80 + nt * 16 + lm;
            const float* src = (row < 256)
                ? gateW + (size_t)row * 384 + 256 + kt * 32 + lh * 8
                : WsW + (size_t)(row - 256) * 128 + kt * 32 + lh * 8;
            float4 f0 = *(const float4*)src;
            float4 f1 = *(const float4*)(src + 4);
            union { unsigned u[4]; short8 s; } tmp;
            tmp.u[0] = cvt_pk(f0.x, f0.y); tmp.u[1] = cvt_pk(f0.z, f0.w);
            tmp.u[2] = cvt_pk(f1.x, f1.y); tmp.u[3] = cvt_pk(f1.z, f1.w);
            bfr[nt][kt] = tmp.s;
        }
    __syncthreads();

    short8 afr[2][4];
#pragma unroll
    for (int mt = 0; mt < 2; mt++)
#pragma unroll
        for (int kt = 0; kt < 4; kt++) {
            int row = mt * 16 + lm;
            afr[mt][kt] = *(const short8*)(a_lds +
                ((row * 256 + kt * 64 + lh * 16) ^ ((row & 7) << 4)));
        }
    f32x4 acc[2][5];
#pragma unroll
    for (int mt = 0; mt < 2; mt++)
#pragma unroll
        for (int nt = 0; nt < 5; nt++) acc[mt][nt] = (f32x4){0.f, 0.f, 0.f, 0.f};
#pragma unroll
    for (int kt = 0; kt < 4; kt++)
#pragma unroll
        for (int mt = 0; mt < 2; mt++)
#pragma unroll
            for (int nt = 0; nt < 5; nt++)
                acc[mt][nt] = __builtin_amdgcn_mfma_f32_16x16x32_bf16(
                    afr[mt][kt], bfr[nt][kt], acc[mt][nt], 0, 0, 0);

#pragma unroll
    for (int mt = 0; mt < 2; mt++)
#pragma unroll
        for (int nt = 0; nt < 5; nt++) {
            int wrow = w * 80 + nt * 16 + lm;
#pragma unroll
            for (int r = 0; r < 4; r++) {
                int node = nbase + mt * 16 + lh * 4 + r;
                if (node < nNode) {
                    ushort_t v = f2bf(acc[mt][nt][r]);
                    if (wrow < 256)
                        gate_hs[(size_t)node * 256 + 2 * (wrow & 127) + (wrow >> 7)] = v;
                    else
                        ws_hs[(size_t)node * 64 + wrow - 256] = v;
                }
            }
        }
}

// ---------------------------------------------------------------------------
// Edge kernel: 32 obj-sorted edges/block, 4 waves; wave w owns dims [32w,32w+32).
// Epilogue run-reduces equal-obj messages in registers before atomicAdd.
// ---------------------------------------------------------------------------
__global__ __launch_bounds__(256, 6) void edge_kernel(
    const int4* __restrict__ sorted, int nEdge,
    const float* __restrict__ grhr, const float* __restrict__ gq,
    const float* __restrict__ whr, const float* __restrict__ wq,
    const float* __restrict__ thr,
    const ushort_t* __restrict__ gate_hs, const ushort_t* __restrict__ ws_hs,
    const ushort_t* __restrict__ hsb,
    const float* __restrict__ walpha, const float* __restrict__ htW,
    float* __restrict__ agg)
{
    __shared__ ushort_t xb[32 * 128];   // 8 KB, x bf16, swz ^((e&7)<<4)
    __shared__ unsigned ab[32 * 128];   // 16 KB, (A,B) bf16 pair, swz ^(((e>>2)&3)<<6)
    __shared__ int4 eds4[32];

    int t = threadIdx.x, w = t >> 6, l = t & 63;
    int lm = l & 15, lh = l >> 4;
    int n0 = w * 32;

    // bijective XCD swizzle: contiguous edge (= obj) ranges per XCD
    int nb = gridDim.x;
    int xcd = blockIdx.x & 7, lid = blockIdx.x >> 3;
    int q = nb >> 3, rr = nb & 7;
    int sbid = ((xcd < rr) ? xcd * (q + 1) : rr * (q + 1) + (xcd - rr) * q) + lid;
    int ebase = sbid * 32;

    if (t < 32) {
        int gi = ebase + t;
        eds4[t] = (gi < nEdge) ? sorted[gi] : make_int4(0, 0, 0, -1);
    }

    short8 bfr[2][4];
#pragma unroll
    for (int nt = 0; nt < 2; nt++)
#pragma unroll
        for (int kt = 0; kt < 4; kt++) {
            const float* src = htW + (size_t)(n0 + nt * 16 + lm) * 256 + 128 + kt * 32 + lh * 8;
            float4 f0 = *(const float4*)src;
            float4 f1 = *(const float4*)(src + 4);
            union { unsigned u[4]; short8 s; } tmp;
            tmp.u[0] = cvt_pk(f0.x, f0.y); tmp.u[1] = cvt_pk(f0.z, f0.w);
            tmp.u[2] = cvt_pk(f1.x, f1.y); tmp.u[3] = cvt_pk(f1.z, f1.w);
            bfr[nt][kt] = tmp.s;
        }
    float wal = walpha[l];
    __syncthreads();   // eds4 ready

    // --- Phase 1: 8 edges per wave ---
#pragma unroll 4
    for (int i = 0; i < 8; i++) {
        int e = w * 8 + i;
        int4 er = eds4[e];
        int ridx = er.x, rel = er.y, sub = er.z;
        ushort4 gp = *(const ushort4*)(gate_hs + (size_t)sub * 256 + 4 * l);
        float4 ga = *(const float4*)(grhr + (size_t)rel * 256 + 4 * l);
        float4 gb = *(const float4*)(gq + (size_t)ridx * 256 + 4 * l);
        unsigned hp = *(const unsigned*)(hsb + (size_t)sub * 128 + 2 * l);
        float h0 = bf2f((ushort_t)(hp & 0xffffu));
        float h1 = bf2f((ushort_t)(hp >> 16));
        float u0 = sigm(ga.x + gb.x + bf2f(gp.x));
        float r0 = sigm(ga.y + gb.y + bf2f(gp.y));
        float u1 = sigm(ga.z + gb.z + bf2f(gp.z));
        float r1 = sigm(ga.w + gb.w + bf2f(gp.w));
        float aa = bf2f(ws_hs[(size_t)sub * 64 + l]) + whr[rel * 64 + l] + wq[ridx * 64 + l];
        aa = (aa > 0.0f) ? aa : 0.01f * aa;
        float v = aa * wal;
#pragma unroll
        for (int o = 32; o > 0; o >>= 1) v += __shfl_xor(v, o, 64);
        float sga = sigm(v);
        unsigned xw = cvt_pk(r0 * h0, r1 * h1);
        *(unsigned*)((char*)xb + ((e * 256 + 4 * l) ^ ((e & 7) << 4))) = xw;
        float A0 = sga * (1.0f - u0) * h0;
        float A1 = sga * (1.0f - u1) * h1;
        uint2 abp;
        abp.x = cvt_pk(A0, sga * u0);
        abp.y = cvt_pk(A1, sga * u1);
        *(uint2*)((char*)ab + ((e * 512 + 8 * l) ^ (((e >> 2) & 3) << 6))) = abp;
    }
    __syncthreads();

    // --- Phase 2: MFMA C[32 edges][32 dims] ---
    short8 afr[2][4];
#pragma unroll
    for (int mt = 0; mt < 2; mt++)
#pragma unroll
        for (int kt = 0; kt < 4; kt++) {
            int e = mt * 16 + lm;
            afr[mt][kt] = *(const short8*)((const char*)xb +
                ((e * 256 + kt * 64 + lh * 16) ^ ((e & 7) << 4)));
        }
    f32x4 acc[2][2];
#pragma unroll
    for (int mt = 0; mt < 2; mt++)
#pragma unroll
        for (int nt = 0; nt < 2; nt++) acc[mt][nt] = (f32x4){0.f, 0.f, 0.f, 0.f};
#pragma unroll
    for (int kt = 0; kt < 4; kt++)
#pragma unroll
        for (int mt = 0; mt < 2; mt++)
#pragma unroll
            for (int nt = 0; nt < 2; nt++)
                acc[mt][nt] = __builtin_amdgcn_mfma_f32_16x16x32_bf16(
                    afr[mt][kt], bfr[nt][kt], acc[mt][nt], 0, 0, 0);

    // --- Epilogue: run-reduced atomics along each lane's 4 consecutive edges ---
#pragma unroll
    for (int mt = 0; mt < 2; mt++)
#pragma unroll
        for (int nt = 0; nt < 2; nt++) {
            int d = n0 + nt * 16 + lm;
            float vals[4];
            int objs[4];
#pragma unroll
            for (int r = 0; r < 4; r++) {
                int e = mt * 16 + lh * 4 + r;
                int rel = eds4[e].y;
                objs[r] = eds4[e].w;
                float th = thr[rel * 128 + d];
                float cand = tanh_fast(acc[mt][nt][r] + th);
                unsigned abw = *(const unsigned*)((const char*)ab +
                    ((e * 512 + 4 * d) ^ (((e >> 2) & 3) << 6)));
                vals[r] = bf2f((ushort_t)(abw & 0xffffu)) +
                          bf2f((ushort_t)(abw >> 16)) * cand;
            }
            float sum = vals[0];
            int prev = objs[0];
#pragma unroll
            for (int r = 1; r < 4; r++) {
                if (objs[r] == prev) {
                    sum += vals[r];
                } else {
                    if (prev >= 0) atomicAdd(agg + (size_t)prev * 128 + d, sum);
                    sum = vals[r];
                    prev = objs[r];
                }
            }
            if (prev >= 0) atomicAdd(agg + (size_t)prev * 128 + d, sum);
        }
}

// ---------------------------------------------------------------------------
// Final (MFMA): out[n] = (agg[n]/sqrt(deg[n]+1e-4)) @ Wh.T, in place.
// ---------------------------------------------------------------------------
__global__ __launch_bounds__(256) void final_kernel(
    const float* __restrict__ WhW, const int* __restrict__ degi,
    float* __restrict__ agg, int nNode)
{
    __shared__ char y_lds[64 * 256];
    int t = threadIdx.x, w = t >> 6, l = t & 63;
    int lm = l & 15, lh = l >> 4;
    int nbase = blockIdx.x * 64;

    short8 bfr[2][4];
#pragma unroll
    for (int nt = 0; nt < 2; nt++)
#pragma unroll
        for (int kt = 0; kt < 4; kt++) {
            const float* src = WhW + (size_t)(w * 32 + nt * 16 + lm) * 128 + kt * 32 + lh * 8;
            float4 f0 = *(const float4*)src;
            float4 f1 = *(const float4*)(src + 4);
            union { unsigned u[4]; short8 s; } tmp;
            tmp.u[0] = cvt_pk(f0.x, f0.y); tmp.u[1] = cvt_pk(f0.z, f0.w);
            tmp.u[2] = cvt_pk(f1.x, f1.y); tmp.u[3] = cvt_pk(f1.z, f1.w);
            bfr[nt][kt] = tmp.s;
        }

    for (int idx = t; idx < 2048; idx += 256) {
        int row = idx >> 5, c4 = idx & 31;
        int node = nbase + row;
        uint2 p = {0u, 0u};
        if (node < nNode) {
            float4 v = ((const float4*)agg)[(size_t)node * 32 + c4];
            float r = 1.0f / sqrtf((float)degi[node] + 1e-4f);
            p.x = cvt_pk(v.x * r, v.y * r);
            p.y = cvt_pk(v.z * r, v.w * r);
        }
        *(uint2*)(y_lds + ((row * 256 + c4 * 8) ^ ((row & 7) << 4))) = p;
    }
    __syncthreads();

    short8 afr[4][4];
#pragma unroll
    for (int mt = 0; mt < 4; mt++)
#pragma unroll
        for (int kt = 0; kt < 4; kt++) {
            int row = mt * 16 + lm;
            afr[mt][kt] = *(const short8*)(y_lds +
                ((row * 256 + kt * 64 + lh * 16) ^ ((row & 7) << 4)));
        }
    f32x4 acc[4][2];
#pragma unroll
    for (int mt = 0; mt < 4; mt++)
#pragma unroll
        for (int nt = 0; nt < 2; nt++) acc[mt][nt] = (f32x4){0.f, 0.f, 0.f, 0.f};
#pragma unroll
    for (int kt = 0; kt < 4; kt++)
#pragma unroll
        for (int mt = 0; mt < 4; mt++)
#pragma unroll
            for (int nt = 0; nt < 2; nt++)
                acc[mt][nt] = __builtin_amdgcn_mfma_f32_16x16x32_bf16(
                    afr[mt][kt], bfr[nt][kt], acc[mt][nt], 0, 0, 0);

#pragma unroll
    for (int mt = 0; mt < 4; mt++)
#pragma unroll
        for (int nt = 0; nt < 2; nt++) {
            int col = w * 32 + nt * 16 + lm;
#pragma unroll
            for (int r = 0; r < 4; r++) {
                int node = nbase + mt * 16 + lh * 4 + r;
                if (node < nNode) agg[(size_t)node * 128 + col] = acc[mt][nt][r];
            }
        }
}

extern "C" void kernel_launch(void* const* d_in, const int* in_sizes, int n_in,
                              void* d_out, int out_size, void* d_ws, size_t ws_size,
                              hipStream_t stream)
{
    const int*   q_rel   = (const int*)d_in[1];
    const float* hidden  = (const float*)d_in[2];
    const int*   edges   = (const int*)d_in[3];
    const float* rela    = (const float*)d_in[5];
    const float* WsW     = (const float*)d_in[6];
    const float* WrW     = (const float*)d_in[7];
    const float* WqrW    = (const float*)d_in[8];
    const float* Wqr_b   = (const float*)d_in[9];
    const float* walpha  = (const float*)d_in[10];
    const float* gateW   = (const float*)d_in[11];
    const float* gateW_b = (const float*)d_in[12];
    const float* htW     = (const float*)d_in[13];
    const float* ht_b    = (const float*)d_in[14];
    const float* WhW     = (const float*)d_in[15];

    int nNode  = in_sizes[2] / 128;
    int nEdge  = in_sizes[3] / 7;
    int vocab  = in_sizes[5] / 128;
    int nQuery = in_sizes[1];

    char* ws = (char*)d_ws;
    size_t off = 0;
    auto alloc = [&](size_t bytes) { size_t o = off; off += (bytes + 255) & ~(size_t)255; return o; };
    int*      cntO    = (int*)(ws + alloc((size_t)(nNode + 256) * 4));
    int*      startO  = (int*)(ws + alloc((size_t)(nNode + 256) * 4));
    int*      cursorO = (int*)(ws + alloc((size_t)(nNode + 256) * 4));
    int*      partials= (int*)(ws + alloc(256 * 4));
    int4*     sorted  = (int4*)(ws + alloc((size_t)nEdge * 16));
    float*    grhr    = (float*)(ws + alloc((size_t)vocab * 256 * 4));
    float*    whr     = (float*)(ws + alloc((size_t)vocab * 64 * 4));
    float*    thr     = (float*)(ws + alloc((size_t)vocab * 128 * 4));
    float*    gq      = (float*)(ws + alloc((size_t)nQuery * 256 * 4));
    float*    wq      = (float*)(ws + alloc((size_t)nQuery * 64 * 4));
    ushort_t* gate_hs = (ushort_t*)(ws + alloc((size_t)nNode * 256 * 2));
    ushort_t* ws_hs   = (ushort_t*)(ws + alloc((size_t)nNode * 64 * 2));
    ushort_t* hsb     = (ushort_t*)(ws + alloc((size_t)nNode * 128 * 2));
    if (off > ws_size) return;

    float* agg = (float*)d_out;
    hipMemsetAsync(agg, 0, (size_t)nNode * 128 * 4, stream);
    hipMemsetAsync(cntO, 0, (size_t)(nNode + 256) * 4, stream);

    // counting sort by obj
    hist_kernel<<<(nEdge + 255) / 256, 256, 0, stream>>>(edges, nEdge, cntO);
    int nScan = nNode + 1;
    int nBlk = (nScan + 255) / 256;
    scan1_kernel<<<nBlk, 256, 0, stream>>>(cntO, nScan, partials);
    scan2_kernel<<<nBlk, 256, 0, stream>>>(cntO, nScan, partials, nBlk, startO, cursorO);
    build_kernel<<<(nEdge + 255) / 256, 256, 0, stream>>>(edges, nEdge, cursorO, sorted);

    table_kernel<<<vocab + nQuery, 256, 0, stream>>>(
        rela, q_rel, gateW, gateW_b, WrW, WqrW, Wqr_b, htW, ht_b,
        grhr, gq, whr, wq, thr, vocab);

    int ngrp = (nNode + 31) / 32;
    node_kernel<<<ngrp, 256, 0, stream>>>(hidden, gateW, WsW, gate_hs, ws_hs, hsb, nNode);

    int eblocks = (nEdge + 31) / 32;
    edge_kernel<<<eblocks, 256, 0, stream>>>(
        sorted, nEdge, grhr, gq, whr, wq, thr,
        gate_hs, ws_hs, hsb, walpha, htW, agg);

    int fblocks = (nNode + 63) / 64;
    final_kernel<<<fblocks, 256, 0, stream>>>(WhW, cntO, agg, nNode);
}

// Round 5
// 375.640 us; speedup vs baseline: 2.0786x; 1.1938x over previous
//
#include <hip/hip_runtime.h>

typedef unsigned short ushort_t;
typedef __attribute__((ext_vector_type(8))) short short8;
typedef __attribute__((ext_vector_type(4))) float f32x4;

#define DEV __device__ __forceinline__

DEV float sigm(float x) { return 1.0f / (1.0f + __expf(-x)); }
DEV float tanh_fast(float x) { return 1.0f - 2.0f / (__expf(2.0f * x) + 1.0f); }
DEV ushort_t f2bf(float v) {
    unsigned u = __float_as_uint(v);
    unsigned r = (u + 0x7fffu + ((u >> 16) & 1u)) >> 16;
    return (ushort_t)r;
}
DEV float bf2f(ushort_t h) { return __uint_as_float(((unsigned)h) << 16); }
DEV unsigned cvt_pk(float lo, float hi) {
    unsigned r;
    asm("v_cvt_pk_bf16_f32 %0, %1, %2" : "=v"(r) : "v"(lo), "v"(hi));
    return r;
}
DEV float dot4(float4 a, float4 b) {
    return fmaf(a.x, b.x, fmaf(a.y, b.y, fmaf(a.z, b.z, a.w * b.w)));
}

// ---------------------------------------------------------------------------
// Fused preprocess kernel: block roles by blockIdx.x.
//  [0, nodeB)              : node precompute (MFMA)
//  [nodeB, nodeB+tableB)   : per-rel / per-query tables
//  [nodeB+tableB, ...)     : obj histogram
// ---------------------------------------------------------------------------
__global__ __launch_bounds__(256) void prep_kernel(
    const float* __restrict__ hidden, const float* __restrict__ gateW,
    const float* __restrict__ WsW,
    ushort_t* __restrict__ gate_hs, ushort_t* __restrict__ ws_hs,
    ushort_t* __restrict__ hsb, int nNode,
    const float* __restrict__ rela, const int* __restrict__ q_rel,
    const float* __restrict__ gateW_b,
    const float* __restrict__ WrW, const float* __restrict__ WqrW,
    const float* __restrict__ Wqr_b, const float* __restrict__ htW,
    const float* __restrict__ ht_b,
    float* __restrict__ grhr, float* __restrict__ gq,
    float* __restrict__ whr, float* __restrict__ wq,
    float* __restrict__ thr, int vocab,
    const int* __restrict__ edges, int nEdge, int* __restrict__ cnt,
    int nodeB, int tableB)
{
    __shared__ char smem[8192];
    int bid = blockIdx.x, t = threadIdx.x;

    if (bid < nodeB) {
        // ---------------- node path ----------------
        char* a_lds = smem;
        int w = t >> 6, l = t & 63;
        int lm = l & 15, lh = l >> 4;
        int nbase = bid * 32;

        for (int idx = t; idx < 1024; idx += 256) {
            int row = idx >> 5, c4 = idx & 31;
            int node = nbase + row;
            float4 v = (node < nNode) ? ((const float4*)hidden)[(size_t)node * 32 + c4]
                                      : float4{0.f, 0.f, 0.f, 0.f};
            uint2 p;
            p.x = cvt_pk(v.x, v.y);
            p.y = cvt_pk(v.z, v.w);
            *(uint2*)(a_lds + ((row * 256 + c4 * 8) ^ ((row & 7) << 4))) = p;
            if (node < nNode) *(uint2*)(hsb + (size_t)node * 128 + c4 * 4) = p;
        }

        short8 bfr[5][4];
#pragma unroll
        for (int nt = 0; nt < 5; nt++)
#pragma unroll
            for (int kt = 0; kt < 4; kt++) {
                int row = w * 80 + nt * 16 + lm;
                const float* src = (row < 256)
                    ? gateW + (size_t)row * 384 + 256 + kt * 32 + lh * 8
                    : WsW + (size_t)(row - 256) * 128 + kt * 32 + lh * 8;
                float4 f0 = *(const float4*)src;
                float4 f1 = *(const float4*)(src + 4);
                union { unsigned u[4]; short8 s; } tmp;
                tmp.u[0] = cvt_pk(f0.x, f0.y); tmp.u[1] = cvt_pk(f0.z, f0.w);
                tmp.u[2] = cvt_pk(f1.x, f1.y); tmp.u[3] = cvt_pk(f1.z, f1.w);
                bfr[nt][kt] = tmp.s;
            }
        __syncthreads();

        short8 afr[2][4];
#pragma unroll
        for (int mt = 0; mt < 2; mt++)
#pragma unroll
            for (int kt = 0; kt < 4; kt++) {
                int row = mt * 16 + lm;
                afr[mt][kt] = *(const short8*)(a_lds +
                    ((row * 256 + kt * 64 + lh * 16) ^ ((row & 7) << 4)));
            }
        f32x4 acc[2][5];
#pragma unroll
        for (int mt = 0; mt < 2; mt++)
#pragma unroll
            for (int nt = 0; nt < 5; nt++) acc[mt][nt] = (f32x4){0.f, 0.f, 0.f, 0.f};
#pragma unroll
        for (int kt = 0; kt < 4; kt++)
#pragma unroll
            for (int mt = 0; mt < 2; mt++)
#pragma unroll
                for (int nt = 0; nt < 5; nt++)
                    acc[mt][nt] = __builtin_amdgcn_mfma_f32_16x16x32_bf16(
                        afr[mt][kt], bfr[nt][kt], acc[mt][nt], 0, 0, 0);

#pragma unroll
        for (int mt = 0; mt < 2; mt++)
#pragma unroll
            for (int nt = 0; nt < 5; nt++) {
                int wrow = w * 80 + nt * 16 + lm;
#pragma unroll
                for (int r = 0; r < 4; r++) {
                    int node = nbase + mt * 16 + lh * 4 + r;
                    if (node < nNode) {
                        ushort_t v = f2bf(acc[mt][nt][r]);
                        if (wrow < 256)
                            gate_hs[(size_t)node * 256 + 2 * (wrow & 127) + (wrow >> 7)] = v;
                        else
                            ws_hs[(size_t)node * 64 + wrow - 256] = v;
                    }
                }
            }
    } else if (bid < nodeB + tableB) {
        // ---------------- table path ----------------
        float* x = (float*)smem;
        int b = bid - nodeB;
        bool isRel = b < vocab;
        int src = isRel ? b : q_rel[b - vocab];
        if (t < 128) x[t] = rela[src * 128 + t];
        __syncthreads();
        const float4* x4 = (const float4*)x;
        {
            const float4* wrow = (const float4*)(gateW + t * 384 + (isRel ? 0 : 128));
            float acc = isRel ? 0.0f : gateW_b[t];
#pragma unroll 8
            for (int i = 0; i < 32; i++) acc += dot4(wrow[i], x4[i]);
            float* dst = isRel ? (grhr + b * 256) : (gq + (b - vocab) * 256);
            dst[2 * (t & 127) + (t >> 7)] = acc;
        }
        if (isRel) {
            if (t < 192) {
                bool isWr = t < 64;
                int i = isWr ? t : (t - 64);
                const float4* wrow = (const float4*)(isWr ? (WrW + i * 128) : (htW + i * 256));
                float acc = isWr ? 0.0f : ht_b[i];
#pragma unroll 8
                for (int q = 0; q < 32; q++) acc += dot4(wrow[q], x4[q]);
                if (isWr) whr[b * 64 + i] = acc;
                else      thr[b * 128 + i] = acc;
            }
        } else {
            if (t < 64) {
                const float4* wrow = (const float4*)(WqrW + t * 128);
                float acc = Wqr_b[t];
#pragma unroll 8
                for (int q = 0; q < 32; q++) acc += dot4(wrow[q], x4[q]);
                wq[(b - vocab) * 64 + t] = acc;
            }
        }
    } else {
        // ---------------- hist path ----------------
        int i = (bid - nodeB - tableB) * 256 + t;
        if (i < nEdge) atomicAdd(cnt + edges[(size_t)i * 7 + 5], 1);
    }
}

// ---------------------------------------------------------------------------
// Scan (two-level) over obj counts.
// ---------------------------------------------------------------------------
__global__ __launch_bounds__(256) void scan1_kernel(
    const int* __restrict__ cnt, int n, int* __restrict__ partials)
{
    __shared__ int s[256];
    int t = threadIdx.x;
    int i = blockIdx.x * 256 + t;
    s[t] = (i < n) ? cnt[i] : 0;
    __syncthreads();
    for (int o = 128; o > 0; o >>= 1) {
        if (t < o) s[t] += s[t + o];
        __syncthreads();
    }
    if (t == 0) partials[blockIdx.x] = s[0];
}

__global__ __launch_bounds__(256) void scan2_kernel(
    const int* __restrict__ cnt, int n, const int* __restrict__ partials,
    int nBlk, int* __restrict__ start, int* __restrict__ cursor)
{
    __shared__ int ps[256];
    __shared__ int loc[256];
    int t = threadIdx.x, b = blockIdx.x;
    ps[t] = (t < nBlk) ? partials[t] : 0;
    __syncthreads();
    for (int o = 1; o < 256; o <<= 1) {
        int v = (t >= o) ? ps[t - o] : 0;
        __syncthreads();
        ps[t] += v;
        __syncthreads();
    }
    int offset = (b > 0) ? ps[b - 1] : 0;
    int i = b * 256 + t;
    int v = (i < n) ? cnt[i] : 0;
    loc[t] = v;
    __syncthreads();
    for (int o = 1; o < 256; o <<= 1) {
        int x = (t >= o) ? loc[t - o] : 0;
        __syncthreads();
        loc[t] += x;
        __syncthreads();
    }
    if (i < n) {
        int excl = offset + loc[t] - v;
        start[i] = excl;
        cursor[i] = excl;
    }
}

__global__ __launch_bounds__(256) void build_kernel(
    const int* __restrict__ edges, int nEdge, int* __restrict__ cursor,
    int4* __restrict__ sorted)
{
    int i = blockIdx.x * 256 + threadIdx.x;
    if (i < nEdge) {
        const int* er = edges + (size_t)i * 7;
        int obj = er[5];
        int s = atomicAdd(cursor + obj, 1);
        sorted[s] = make_int4(er[0], er[2], er[4], obj);
    }
}

// ---------------------------------------------------------------------------
// Edge kernel: 32 obj-sorted edges/block, 4 waves; wave w owns dims [32w,32w+32).
// Loop A: independent per-edge gather+gates+x/AB-stores (pre-sga), aa partial.
// Then: thr -> acc init, batched 8-way butterflies, sga -> LDS.
// Phase 2: MFMA (C pre-loaded with thr). Epilogue: run-reduced atomics.
// ---------------------------------------------------------------------------
__global__ __launch_bounds__(256, 6) void edge_kernel(
    const int4* __restrict__ sorted, int nEdge,
    const float* __restrict__ grhr, const float* __restrict__ gq,
    const float* __restrict__ whr, const float* __restrict__ wq,
    const float* __restrict__ thr,
    const ushort_t* __restrict__ gate_hs, const ushort_t* __restrict__ ws_hs,
    const ushort_t* __restrict__ hsb,
    const float* __restrict__ walpha, const float* __restrict__ htW,
    float* __restrict__ agg)
{
    __shared__ ushort_t xb[32 * 128];   // 8 KB, x bf16, swz ^((e&7)<<4)
    __shared__ unsigned ab[32 * 128];   // 16 KB, (A',B') bf16 pair, swz ^(((e>>2)&3)<<6)
    __shared__ float sgaL[32];
    __shared__ int4 eds4[32];

    int t = threadIdx.x, w = t >> 6, l = t & 63;
    int lm = l & 15, lh = l >> 4;
    int n0 = w * 32;

    // bijective XCD swizzle: contiguous edge (= obj) ranges per XCD
    int nb = gridDim.x;
    int xcd = blockIdx.x & 7, lid = blockIdx.x >> 3;
    int q = nb >> 3, rr = nb & 7;
    int sbid = ((xcd < rr) ? xcd * (q + 1) : rr * (q + 1) + (xcd - rr) * q) + lid;
    int ebase = sbid * 32;

    if (t < 32) {
        int gi = ebase + t;
        eds4[t] = (gi < nEdge) ? sorted[gi] : make_int4(0, 0, 0, -1);
    }

    // B fragments (W2 = htW[:,128:256] bf16) in VGPRs
    short8 bfr[2][4];
#pragma unroll
    for (int nt = 0; nt < 2; nt++)
#pragma unroll
        for (int kt = 0; kt < 4; kt++) {
            const float* src = htW + (size_t)(n0 + nt * 16 + lm) * 256 + 128 + kt * 32 + lh * 8;
            float4 f0 = *(const float4*)src;
            float4 f1 = *(const float4*)(src + 4);
            union { unsigned u[4]; short8 s; } tmp;
            tmp.u[0] = cvt_pk(f0.x, f0.y); tmp.u[1] = cvt_pk(f0.z, f0.w);
            tmp.u[2] = cvt_pk(f1.x, f1.y); tmp.u[3] = cvt_pk(f1.z, f1.w);
            bfr[nt][kt] = tmp.s;
        }
    float wal = walpha[l];
    __syncthreads();   // eds4 ready

    // --- Loop A: independent per-edge work ---
    float aa8[8];
#pragma unroll
    for (int i = 0; i < 8; i++) {
        int e = w * 8 + i;
        int4 er = eds4[e];
        int ridx = er.x, rel = er.y, sub = er.z;
        ushort4 gp = *(const ushort4*)(gate_hs + (size_t)sub * 256 + 4 * l);
        float4 ga = *(const float4*)(grhr + (size_t)rel * 256 + 4 * l);
        float4 gb = *(const float4*)(gq + (size_t)ridx * 256 + 4 * l);
        unsigned hp = *(const unsigned*)(hsb + (size_t)sub * 128 + 2 * l);
        float aw = bf2f(ws_hs[(size_t)sub * 64 + l]) + whr[rel * 64 + l] + wq[ridx * 64 + l];
        float h0 = bf2f((ushort_t)(hp & 0xffffu));
        float h1 = bf2f((ushort_t)(hp >> 16));
        float u0 = sigm(ga.x + gb.x + bf2f(gp.x));
        float r0 = sigm(ga.y + gb.y + bf2f(gp.y));
        float u1 = sigm(ga.z + gb.z + bf2f(gp.z));
        float r1 = sigm(ga.w + gb.w + bf2f(gp.w));
        *(unsigned*)((char*)xb + ((e * 256 + 4 * l) ^ ((e & 7) << 4))) = cvt_pk(r0 * h0, r1 * h1);
        uint2 abp;
        abp.x = cvt_pk((1.0f - u0) * h0, u0);
        abp.y = cvt_pk((1.0f - u1) * h1, u1);
        *(uint2*)((char*)ab + ((e * 512 + 8 * l) ^ (((e >> 2) & 3) << 6))) = abp;
        aw = (aw > 0.0f) ? aw : 0.01f * aw;
        aa8[i] = aw * wal;
    }

    // --- acc init = thr[rel][d] (C of MFMA); latency hidden under butterflies ---
    f32x4 acc[2][2];
#pragma unroll
    for (int mt = 0; mt < 2; mt++)
#pragma unroll
        for (int nt = 0; nt < 2; nt++) {
            int d = n0 + nt * 16 + lm;
#pragma unroll
            for (int r = 0; r < 4; r++) {
                int rel = eds4[mt * 16 + lh * 4 + r].y;
                acc[mt][nt][r] = thr[rel * 128 + d];
            }
        }

    // --- batched butterflies (8-way ILP) ---
#pragma unroll
    for (int o = 32; o > 0; o >>= 1) {
#pragma unroll
        for (int i = 0; i < 8; i++) aa8[i] += __shfl_xor(aa8[i], o, 64);
    }
#pragma unroll
    for (int i = 0; i < 8; i++) {
        float s = sigm(aa8[i]);
        if (l == i) sgaL[w * 8 + i] = s;
    }
    __syncthreads();

    // --- Phase 2: MFMA C[32 edges][32 dims] (C pre-loaded with thr) ---
    short8 afr[2][4];
#pragma unroll
    for (int mt = 0; mt < 2; mt++)
#pragma unroll
        for (int kt = 0; kt < 4; kt++) {
            int e = mt * 16 + lm;
            afr[mt][kt] = *(const short8*)((const char*)xb +
                ((e * 256 + kt * 64 + lh * 16) ^ ((e & 7) << 4)));
        }
#pragma unroll
    for (int kt = 0; kt < 4; kt++)
#pragma unroll
        for (int mt = 0; mt < 2; mt++)
#pragma unroll
            for (int nt = 0; nt < 2; nt++)
                acc[mt][nt] = __builtin_amdgcn_mfma_f32_16x16x32_bf16(
                    afr[mt][kt], bfr[nt][kt], acc[mt][nt], 0, 0, 0);

    // --- Epilogue: run-reduced atomics along each lane's 4 consecutive edges ---
#pragma unroll
    for (int mt = 0; mt < 2; mt++)
#pragma unroll
        for (int nt = 0; nt < 2; nt++) {
            int d = n0 + nt * 16 + lm;
            float vals[4];
            int objs[4];
#pragma unroll
            for (int r = 0; r < 4; r++) {
                int e = mt * 16 + lh * 4 + r;
                objs[r] = eds4[e].w;
                float cand = tanh_fast(acc[mt][nt][r]);
                unsigned abw = *(const unsigned*)((const char*)ab +
                    ((e * 512 + 4 * d) ^ (((e >> 2) & 3) << 6)));
                float sg = sgaL[e];
                vals[r] = sg * (bf2f((ushort_t)(abw & 0xffffu)) +
                                bf2f((ushort_t)(abw >> 16)) * cand);
            }
            float sum = vals[0];
            int prev = objs[0];
#pragma unroll
            for (int r = 1; r < 4; r++) {
                if (objs[r] == prev) {
                    sum += vals[r];
                } else {
                    if (prev >= 0) atomicAdd(agg + (size_t)prev * 128 + d, sum);
                    sum = vals[r];
                    prev = objs[r];
                }
            }
            if (prev >= 0) atomicAdd(agg + (size_t)prev * 128 + d, sum);
        }
}

// ---------------------------------------------------------------------------
// Final (MFMA): out[n] = (agg[n]/sqrt(deg[n]+1e-4)) @ Wh.T, in place.
// ---------------------------------------------------------------------------
__global__ __launch_bounds__(256) void final_kernel(
    const float* __restrict__ WhW, const int* __restrict__ degi,
    float* __restrict__ agg, int nNode)
{
    __shared__ char y_lds[64 * 256];
    int t = threadIdx.x, w = t >> 6, l = t & 63;
    int lm = l & 15, lh = l >> 4;
    int nbase = blockIdx.x * 64;

    short8 bfr[2][4];
#pragma unroll
    for (int nt = 0; nt < 2; nt++)
#pragma unroll
        for (int kt = 0; kt < 4; kt++) {
            const float* src = WhW + (size_t)(w * 32 + nt * 16 + lm) * 128 + kt * 32 + lh * 8;
            float4 f0 = *(const float4*)src;
            float4 f1 = *(const float4*)(src + 4);
            union { unsigned u[4]; short8 s; } tmp;
            tmp.u[0] = cvt_pk(f0.x, f0.y); tmp.u[1] = cvt_pk(f0.z, f0.w);
            tmp.u[2] = cvt_pk(f1.x, f1.y); tmp.u[3] = cvt_pk(f1.z, f1.w);
            bfr[nt][kt] = tmp.s;
        }

    for (int idx = t; idx < 2048; idx += 256) {
        int row = idx >> 5, c4 = idx & 31;
        int node = nbase + row;
        uint2 p = {0u, 0u};
        if (node < nNode) {
            float4 v = ((const float4*)agg)[(size_t)node * 32 + c4];
            float r = 1.0f / sqrtf((float)degi[node] + 1e-4f);
            p.x = cvt_pk(v.x * r, v.y * r);
            p.y = cvt_pk(v.z * r, v.w * r);
        }
        *(uint2*)(y_lds + ((row * 256 + c4 * 8) ^ ((row & 7) << 4))) = p;
    }
    __syncthreads();

    short8 afr[4][4];
#pragma unroll
    for (int mt = 0; mt < 4; mt++)
#pragma unroll
        for (int kt = 0; kt < 4; kt++) {
            int row = mt * 16 + lm;
            afr[mt][kt] = *(const short8*)(y_lds +
                ((row * 256 + kt * 64 + lh * 16) ^ ((row & 7) << 4)));
        }
    f32x4 acc[4][2];
#pragma unroll
    for (int mt = 0; mt < 4; mt++)
#pragma unroll
        for (int nt = 0; nt < 2; nt++) acc[mt][nt] = (f32x4){0.f, 0.f, 0.f, 0.f};
#pragma unroll
    for (int kt = 0; kt < 4; kt++)
#pragma unroll
        for (int mt = 0; mt < 4; mt++)
#pragma unroll
            for (int nt = 0; nt < 2; nt++)
                acc[mt][nt] = __builtin_amdgcn_mfma_f32_16x16x32_bf16(
                    afr[mt][kt], bfr[nt][kt], acc[mt][nt], 0, 0, 0);

#pragma unroll
    for (int mt = 0; mt < 4; mt++)
#pragma unroll
        for (int nt = 0; nt < 2; nt++) {
            int col = w * 32 + nt * 16 + lm;
#pragma unroll
            for (int r = 0; r < 4; r++) {
                int node = nbase + mt * 16 + lh * 4 + r;
                if (node < nNode) agg[(size_t)node * 128 + col] = acc[mt][nt][r];
            }
        }
}

extern "C" void kernel_launch(void* const* d_in, const int* in_sizes, int n_in,
                              void* d_out, int out_size, void* d_ws, size_t ws_size,
                              hipStream_t stream)
{
    const int*   q_rel   = (const int*)d_in[1];
    const float* hidden  = (const float*)d_in[2];
    const int*   edges   = (const int*)d_in[3];
    const float* rela    = (const float*)d_in[5];
    const float* WsW     = (const float*)d_in[6];
    const float* WrW     = (const float*)d_in[7];
    const float* WqrW    = (const float*)d_in[8];
    const float* Wqr_b   = (const float*)d_in[9];
    const float* walpha  = (const float*)d_in[10];
    const float* gateW   = (const float*)d_in[11];
    const float* gateW_b = (const float*)d_in[12];
    const float* htW     = (const float*)d_in[13];
    const float* ht_b    = (const float*)d_in[14];
    const float* WhW     = (const float*)d_in[15];

    int nNode  = in_sizes[2] / 128;
    int nEdge  = in_sizes[3] / 7;
    int vocab  = in_sizes[5] / 128;
    int nQuery = in_sizes[1];

    char* ws = (char*)d_ws;
    size_t off = 0;
    auto alloc = [&](size_t bytes) { size_t o = off; off += (bytes + 255) & ~(size_t)255; return o; };
    int*      cntO    = (int*)(ws + alloc((size_t)(nNode + 256) * 4));
    int*      startO  = (int*)(ws + alloc((size_t)(nNode + 256) * 4));
    int*      cursorO = (int*)(ws + alloc((size_t)(nNode + 256) * 4));
    int*      partials= (int*)(ws + alloc(256 * 4));
    int4*     sorted  = (int4*)(ws + alloc((size_t)nEdge * 16));
    float*    grhr    = (float*)(ws + alloc((size_t)vocab * 256 * 4));
    float*    whr     = (float*)(ws + alloc((size_t)vocab * 64 * 4));
    float*    thr     = (float*)(ws + alloc((size_t)vocab * 128 * 4));
    float*    gq      = (float*)(ws + alloc((size_t)nQuery * 256 * 4));
    float*    wq      = (float*)(ws + alloc((size_t)nQuery * 64 * 4));
    ushort_t* gate_hs = (ushort_t*)(ws + alloc((size_t)nNode * 256 * 2));
    ushort_t* ws_hs   = (ushort_t*)(ws + alloc((size_t)nNode * 64 * 2));
    ushort_t* hsb     = (ushort_t*)(ws + alloc((size_t)nNode * 128 * 2));
    if (off > ws_size) return;

    float* agg = (float*)d_out;
    hipMemsetAsync(agg, 0, (size_t)nNode * 128 * 4, stream);
    hipMemsetAsync(cntO, 0, (size_t)(nNode + 256) * 4, stream);

    int nodeB  = (nNode + 31) / 32;
    int tableB = vocab + nQuery;
    int histB  = (nEdge + 255) / 256;
    prep_kernel<<<nodeB + tableB + histB, 256, 0, stream>>>(
        hidden, gateW, WsW, gate_hs, ws_hs, hsb, nNode,
        rela, q_rel, gateW_b, WrW, WqrW, Wqr_b, htW, ht_b,
        grhr, gq, whr, wq, thr, vocab,
        edges, nEdge, cntO, nodeB, tableB);

    int nScan = nNode + 1;
    int nBlk = (nScan + 255) / 256;
    scan1_kernel<<<nBlk, 256, 0, stream>>>(cntO, nScan, partials);
    scan2_kernel<<<nBlk, 256, 0, stream>>>(cntO, nScan, partials, nBlk, startO, cursorO);
    build_kernel<<<(nEdge + 255) / 256, 256, 0, stream>>>(edges, nEdge, cursorO, sorted);

    int eblocks = (nEdge + 31) / 32;
    edge_kernel<<<eblocks, 256, 0, stream>>>(
        sorted, nEdge, grhr, gq, whr, wq, thr,
        gate_hs, ws_hs, hsb, walpha, htW, agg);

    int fblocks = (nNode + 63) / 64;
    final_kernel<<<fblocks, 256, 0, stream>>>(WhW, cntO, agg, nNode);
}